// Round 3
// baseline (784.862 us; speedup 1.0000x reference)
//
#include <hip/hip_runtime.h>
#include <hip/hip_bf16.h>
#include <math.h>

constexpr int NB = 64;     // batch
constexpr int NS = 2048;   // tokens
constexpr int ND = 1024;   // model dim
constexpr int NE = 32;     // experts
constexpr int NH = 4096;   // hidden
constexpr int NK = 8;      // top-k tokens per expert

typedef short bf16x8 __attribute__((ext_vector_type(8)));
typedef float f32x4  __attribute__((ext_vector_type(4)));

// fp32 -> (hi, lo) bf16 split; 3-term MFMA gives ~2^-16 rel error.
__device__ __forceinline__ unsigned short f2bf_rne(float v) {
  unsigned u = __builtin_bit_cast(unsigned, v);
  u += 0x7fffu + ((u >> 16) & 1u);
  return (unsigned short)(u >> 16);
}
__device__ __forceinline__ void split_bf16(float v, unsigned short& h, unsigned short& l) {
  h = f2bf_rne(v);
  float fh = __builtin_bit_cast(float, (unsigned)h << 16);
  l = f2bf_rne(v - fh);
}

// ---------------------------------------------------------------------------
// Kernel 1: gating GEMM via split-bf16 MFMA. logitsT[b][e][s] (approx, ~1e-5).
// Selection correctness is restored by the fp64 recheck in k_topk.
// Gate bias cancels in softmax (and is zero in setup) -> ignored.
// Block: 128 tokens x 32 experts, BK=64, 4 waves, T14 reg-prefetch.
// ---------------------------------------------------------------------------
__global__ __launch_bounds__(256) void k_gate_mfma(const float* __restrict__ x,
                                                   const float* __restrict__ gw,
                                                   float* __restrict__ logitsT) {
  const int b  = blockIdx.y;
  const int s0 = blockIdx.x * 128;
  const int t  = threadIdx.x;
  const int l  = t & 63;
  const int w  = t >> 6;

  __shared__ char smem[40960];
  short* Ah = (short*)smem;            // [128][64] swz bf16 hi, 16KB
  short* Al = (short*)(smem + 16384);  // lo, 16KB
  short* Bh = (short*)(smem + 32768);  // [32][64] swz, 4KB
  short* Bl = (short*)(smem + 36864);  // 4KB
  float* trans = (float*)smem;         // [128][33] f32 epilogue (reuses Ah/Al)

  f32x4 acc[2][2] = {};

  const int xr_ = t >> 4, xc = (t & 15) * 4;   // x staging: 16 thr/row
  const int ge = t >> 3,  gk = (t & 7) * 8;    // gw staging: 8 thr/row

  float xreg[8][4];
  float wreg[8];

  auto issue = [&](int k0) {
#pragma unroll
    for (int p = 0; p < 8; ++p) {
      const int r = p * 16 + xr_;
      *(float4*)xreg[p] = *(const float4*)&x[((size_t)b * NS + s0 + r) * ND + k0 + xc];
    }
    *(float4*)&wreg[0] = *(const float4*)&gw[(size_t)ge * ND + k0 + gk];
    *(float4*)&wreg[4] = *(const float4*)&gw[(size_t)ge * ND + k0 + gk + 4];
  };
  auto commit = [&]() {
#pragma unroll
    for (int p = 0; p < 8; ++p) {
      const int r = p * 16 + xr_;
      unsigned short h[4], lo[4];
#pragma unroll
      for (int j = 0; j < 4; ++j) split_bf16(xreg[p][j], h[j], lo[j]);
      const int off = r * 64 + (xc ^ ((r & 7) * 8));
      *(ushort4*)&Ah[off] = make_ushort4(h[0], h[1], h[2], h[3]);
      *(ushort4*)&Al[off] = make_ushort4(lo[0], lo[1], lo[2], lo[3]);
    }
    unsigned short h8[8], l8[8];
#pragma unroll
    for (int j = 0; j < 8; ++j) split_bf16(wreg[j], h8[j], l8[j]);
    const int boff = ge * 64 + (gk ^ ((ge & 7) * 8));
    *(uint4*)&Bh[boff] = *(const uint4*)h8;
    *(uint4*)&Bl[boff] = *(const uint4*)l8;
  };

  issue(0);
  for (int k0 = 0; k0 < ND; k0 += 64) {
    commit();
    __syncthreads();
    if (k0 + 64 < ND) issue(k0 + 64);
#pragma unroll
    for (int ks = 0; ks < 2; ++ks) {
      const int koff = ks * 32 + (l >> 4) * 8;
      bf16x8 ah[2], alo[2], bh[2], blo[2];
#pragma unroll
      for (int mf = 0; mf < 2; ++mf) {
        const int r   = w * 32 + mf * 16 + (l & 15);
        const int off = r * 64 + (koff ^ ((r & 7) * 8));
        ah[mf]  = *(const bf16x8*)&Ah[off];
        alo[mf] = *(const bf16x8*)&Al[off];
      }
#pragma unroll
      for (int nf = 0; nf < 2; ++nf) {
        const int n   = nf * 16 + (l & 15);
        const int off = n * 64 + (koff ^ ((n & 7) * 8));
        bh[nf]  = *(const bf16x8*)&Bh[off];
        blo[nf] = *(const bf16x8*)&Bl[off];
      }
#pragma unroll
      for (int mf = 0; mf < 2; ++mf)
#pragma unroll
        for (int nf = 0; nf < 2; ++nf) {
          acc[mf][nf] = __builtin_amdgcn_mfma_f32_16x16x32_bf16(ah[mf],  bh[nf],  acc[mf][nf], 0, 0, 0);
          acc[mf][nf] = __builtin_amdgcn_mfma_f32_16x16x32_bf16(alo[mf], bh[nf],  acc[mf][nf], 0, 0, 0);
          acc[mf][nf] = __builtin_amdgcn_mfma_f32_16x16x32_bf16(ah[mf],  blo[nf], acc[mf][nf], 0, 0, 0);
        }
    }
    __syncthreads();
  }
  // transpose epilogue through LDS for coalesced [e][s] stores
#pragma unroll
  for (int mf = 0; mf < 2; ++mf)
#pragma unroll
    for (int nf = 0; nf < 2; ++nf)
#pragma unroll
      for (int j = 0; j < 4; ++j) {
        const int sl = w * 32 + mf * 16 + (l >> 4) * 4 + j;
        const int ec = nf * 16 + (l & 15);
        trans[sl * 33 + ec] = acc[mf][nf][j];
      }
  __syncthreads();
  const int eo = t >> 3, sc = (t & 7) * 16;
#pragma unroll
  for (int j4 = 0; j4 < 4; ++j4) {
    float4 v;
    v.x = trans[(sc + j4 * 4 + 0) * 33 + eo];
    v.y = trans[(sc + j4 * 4 + 1) * 33 + eo];
    v.z = trans[(sc + j4 * 4 + 2) * 33 + eo];
    v.w = trans[(sc + j4 * 4 + 3) * 33 + eo];
    *(float4*)&logitsT[((size_t)b * NE + eo) * NS + s0 + sc + j4 * 4] = v;
  }
}

// ---------------------------------------------------------------------------
// Kernel 2: per (b,e): approx top-16 + softmax denom from approx logits, then
// exact fp64 recompute of the 16 candidate logits -> exact top-8 ordering
// (identical selection to a full-fp64 gate). One wave per (b,e).
// ---------------------------------------------------------------------------
__global__ __launch_bounds__(64) void k_topk(const float* __restrict__ logitsT,
                                             const float* __restrict__ x,
                                             const float* __restrict__ gw,
                                             float* __restrict__ tval,
                                             int* __restrict__ tidx) {
  const int be = blockIdx.x;
  const int b = be >> 5, e = be & 31;
  const float* row = logitsT + (size_t)be * NS;
  const int lane = threadIdx.x;

  // per-lane top-8 (ascending) + max
  float p8[8]; int i8[8];
#pragma unroll
  for (int j = 0; j < 8; ++j) { p8[j] = -INFINITY; i8[j] = 0x7fffffff; }
  float mx = -INFINITY;
  for (int s = lane; s < NS; s += 64) {
    float lv = row[s];
    mx = fmaxf(mx, lv);
    if (lv > p8[0] || (lv == p8[0] && s < i8[0])) {
      int pos = 0;
#pragma unroll
      for (int j = 1; j < 8; ++j) {
        if (lv > p8[j] || (lv == p8[j] && s < i8[j])) {
          p8[j - 1] = p8[j]; i8[j - 1] = i8[j]; pos = j;
        } else break;
      }
      p8[pos] = lv; i8[pos] = s;
    }
  }
#pragma unroll
  for (int off = 32; off; off >>= 1) mx = fmaxf(mx, __shfl_xor(mx, off));
  // softmax denominator (approx logits; consistent with approx numerator mx)
  double sum = 0.0;
  for (int s = lane; s < NS; s += 64) sum += (double)expf(row[s] - mx);
#pragma unroll
  for (int off = 32; off; off >>= 1) sum += __shfl_xor(sum, off);
  const double inv = 1.0 / sum;

  // extract global approx top-16 (value desc, idx asc)
  int ci[16];
  int ptr = 7;
#pragma unroll
  for (int r = 0; r < 16; ++r) {
    float bp = (ptr >= 0) ? p8[ptr] : -INFINITY;
    int   bi = (ptr >= 0) ? i8[ptr] : 0x7fffffff;
    int   bl = lane;
#pragma unroll
    for (int off = 1; off < 64; off <<= 1) {
      float op = __shfl_xor(bp, off);
      int   oi = __shfl_xor(bi, off);
      int   ol = __shfl_xor(bl, off);
      if (op > bp || (op == bp && oi < bi)) { bp = op; bi = oi; bl = ol; }
    }
    ci[r] = bi;
    if (lane == bl) ptr--;
  }

  // exact fp64 logits for the 16 candidates
  const int kb = lane * 16;
  float gwl[16];
  *(float4*)&gwl[0]  = *(const float4*)&gw[(size_t)e * ND + kb + 0];
  *(float4*)&gwl[4]  = *(const float4*)&gw[(size_t)e * ND + kb + 4];
  *(float4*)&gwl[8]  = *(const float4*)&gw[(size_t)e * ND + kb + 8];
  *(float4*)&gwl[12] = *(const float4*)&gw[(size_t)e * ND + kb + 12];
  float lc[16];
#pragma unroll
  for (int c = 0; c < 16; ++c) {
    const float* xr2 = x + ((size_t)b * NS + ci[c]) * ND + kb;
    float xv[16];
    *(float4*)&xv[0]  = *(const float4*)&xr2[0];
    *(float4*)&xv[4]  = *(const float4*)&xr2[4];
    *(float4*)&xv[8]  = *(const float4*)&xr2[8];
    *(float4*)&xv[12] = *(const float4*)&xr2[12];
    double d = 0.0;
#pragma unroll
    for (int j = 0; j < 16; ++j) d += (double)xv[j] * (double)gwl[j];
#pragma unroll
    for (int off = 32; off; off >>= 1) d += __shfl_xor(d, off);
    lc[c] = (float)d;
  }
  // rank (desc by value, ties -> lower idx) and emit top-8
  int rank[16];
#pragma unroll
  for (int c = 0; c < 16; ++c) {
    int r = 0;
#pragma unroll
    for (int c2 = 0; c2 < 16; ++c2)
      if (c2 != c)
        r += (lc[c2] > lc[c]) || (lc[c2] == lc[c] && ci[c2] < ci[c]);
    rank[c] = r;
  }
  if (lane == 0) {
#pragma unroll
    for (int c = 0; c < 16; ++c)
      if (rank[c] < 8) {
        tval[be * 8 + rank[c]] = (float)((double)expf(lc[c] - mx) * inv);
        tidx[be * 8 + rank[c]] = ci[c];
      }
  }
}

// ---------------------------------------------------------------------------
// Kernel 3: mux/merge -> split-bf16 A in FFN layout [e][m=b][k=d]
// ---------------------------------------------------------------------------
__global__ __launch_bounds__(256) void k_merge(const float* __restrict__ x,
                                               const float* __restrict__ tval,
                                               const int* __restrict__ tidx,
                                               unsigned short* __restrict__ Ah,
                                               unsigned short* __restrict__ Al) {
  const int be = blockIdx.x;
  const int b  = be >> 5;
  const int e  = be & 31;
  const int t  = threadIdx.x;
  float4 acc = {0.f, 0.f, 0.f, 0.f};
#pragma unroll
  for (int k = 0; k < 8; ++k) {
    float v = tval[be * 8 + k];
    int   s = tidx[be * 8 + k];
    float4 xv = *(const float4*)&x[((size_t)b * NS + s) * ND + t * 4];
    acc.x += v * xv.x; acc.y += v * xv.y; acc.z += v * xv.z; acc.w += v * xv.w;
  }
  unsigned short h[4], lo[4];
  split_bf16(acc.x, h[0], lo[0]); split_bf16(acc.y, h[1], lo[1]);
  split_bf16(acc.z, h[2], lo[2]); split_bf16(acc.w, h[3], lo[3]);
  const size_t o = ((size_t)e * 64 + b) * ND + t * 4;
  *(ushort4*)&Ah[o] = make_ushort4(h[0], h[1], h[2], h[3]);
  *(ushort4*)&Al[o] = make_ushort4(lo[0], lo[1], lo[2], lo[3]);
}

// ---------------------------------------------------------------------------
// Kernels 4/5: per-expert FFN GEMM, split-bf16 MFMA, T14 reg-prefetch:
// issue next tile's global loads before the MFMA phase, convert+ds_write
// after the trailing barrier -> HBM latency hides under compute.
// ---------------------------------------------------------------------------
template <int K, int N, bool GELU>
__global__ __launch_bounds__(256) void k_ffn_mfma(const unsigned short* __restrict__ Agh,
                                                  const unsigned short* __restrict__ Agl,
                                                  const float* __restrict__ W,
                                                  unsigned short* __restrict__ Oh,
                                                  unsigned short* __restrict__ Ol,
                                                  float* __restrict__ Of) {
  const int e  = blockIdx.y;
  const int n0 = blockIdx.x * 128;
  const int t  = threadIdx.x;
  const int l  = t & 63;
  const int w  = t >> 6;
  const int wr = w >> 1, wc = w & 1;

  __shared__ short Ah[64 * 64], Al[64 * 64];    // [m][k^swz]  8KB each
  __shared__ short Bh[128 * 64], Bl[128 * 64];  // [n][k^swz] 16KB each

  const float* Wbase = W + (size_t)e * (K + 1) * N;

  f32x4 acc[2][4] = {};
  const int am = t >> 2;       // A staging row
  const int ac = (t & 3) * 2;  // A staging chunk pair
  const int nb = t & 31;       // W staging n
  const int kb = t >> 5;       // W staging k-block (8 rows)

  uint4 pAh[2], pAl[2];
  float pW[8][4];

  auto issue = [&](int k0) {
    const size_t g = ((size_t)e * 64 + am) * K + k0;
#pragma unroll
    for (int q = 0; q < 2; ++q) {
      pAh[q] = *(const uint4*)&Agh[g + (ac + q) * 8];
      pAl[q] = *(const uint4*)&Agl[g + (ac + q) * 8];
    }
    const float* Wg = Wbase + (size_t)(k0 + kb * 8) * N + n0 + nb;
#pragma unroll
    for (int i = 0; i < 8; ++i)
#pragma unroll
      for (int j = 0; j < 4; ++j) pW[i][j] = Wg[(size_t)i * N + 32 * j];
  };
  auto commit = [&]() {
#pragma unroll
    for (int q = 0; q < 2; ++q) {
      const int ks  = (ac + q) * 8;
      const int off = am * 64 + (ks ^ ((am & 7) * 8));
      *(uint4*)&Ah[off] = pAh[q];
      *(uint4*)&Al[off] = pAl[q];
    }
#pragma unroll
    for (int j = 0; j < 4; ++j) {
      const int n = nb + 32 * j;
      unsigned short h8[8], l8[8];
#pragma unroll
      for (int i = 0; i < 8; ++i) split_bf16(pW[i][j], h8[i], l8[i]);
      const int off = n * 64 + ((kb * 8) ^ ((n & 7) * 8));
      *(uint4*)&Bh[off] = *(const uint4*)h8;
      *(uint4*)&Bl[off] = *(const uint4*)l8;
    }
  };

  issue(0);
  for (int k0 = 0; k0 < K; k0 += 64) {
    commit();
    __syncthreads();
    if (k0 + 64 < K) issue(k0 + 64);
#pragma unroll
    for (int ks = 0; ks < 2; ++ks) {
      const int koff = ks * 32 + (l >> 4) * 8;
      bf16x8 ah[2], alo[2], bh[4], blo[4];
#pragma unroll
      for (int mf = 0; mf < 2; ++mf) {
        const int r   = wr * 32 + mf * 16 + (l & 15);
        const int off = r * 64 + (koff ^ ((r & 7) * 8));
        ah[mf]  = *(const bf16x8*)&Ah[off];
        alo[mf] = *(const bf16x8*)&Al[off];
      }
#pragma unroll
      for (int nf = 0; nf < 4; ++nf) {
        const int n   = wc * 64 + nf * 16 + (l & 15);
        const int off = n * 64 + (koff ^ ((n & 7) * 8));
        bh[nf]  = *(const bf16x8*)&Bh[off];
        blo[nf] = *(const bf16x8*)&Bl[off];
      }
#pragma unroll
      for (int mf = 0; mf < 2; ++mf)
#pragma unroll
        for (int nf = 0; nf < 4; ++nf) {
          acc[mf][nf] = __builtin_amdgcn_mfma_f32_16x16x32_bf16(ah[mf],  bh[nf],  acc[mf][nf], 0, 0, 0);
          acc[mf][nf] = __builtin_amdgcn_mfma_f32_16x16x32_bf16(alo[mf], bh[nf],  acc[mf][nf], 0, 0, 0);
          acc[mf][nf] = __builtin_amdgcn_mfma_f32_16x16x32_bf16(ah[mf],  blo[nf], acc[mf][nf], 0, 0, 0);
        }
    }
    __syncthreads();
  }
#pragma unroll
  for (int nf = 0; nf < 4; ++nf) {
    const int   c    = n0 + wc * 64 + nf * 16 + (l & 15);
    const float bias = Wbase[(size_t)K * N + c];
#pragma unroll
    for (int mf = 0; mf < 2; ++mf) {
#pragma unroll
      for (int j = 0; j < 4; ++j) {
        const int m = wr * 32 + mf * 16 + (l >> 4) * 4 + j;
        float v = acc[mf][nf][j] + bias;
        if (GELU) {
          v = 0.5f * v * (1.0f + erff(v * 0.70710678118654752440f));
          unsigned short h, lo;
          split_bf16(v, h, lo);
          Oh[((size_t)e * 64 + m) * N + c] = h;
          Ol[((size_t)e * 64 + m) * N + c] = lo;
        } else {
          Of[((size_t)m * NE + e) * N + c] = v;
        }
      }
    }
  }
}

// ---------------------------------------------------------------------------
// Kernel 6: demux/scatter (deterministic, atomic-free, zero-fills).
// ---------------------------------------------------------------------------
__global__ __launch_bounds__(256) void k_scatter(const float* __restrict__ Obuf,
                                                 const float* __restrict__ tval,
                                                 const int* __restrict__ tidx,
                                                 float* __restrict__ out) {
  const int s = blockIdx.x;
  const int b = blockIdx.y;
  const int t = threadIdx.x;
  __shared__ unsigned long long masks[4];

  const int myIdx = tidx[b * 256 + t];
  unsigned long long m = __ballot(myIdx == s);
  if ((t & 63) == 0) masks[t >> 6] = m;
  __syncthreads();

  float4 acc = {0.f, 0.f, 0.f, 0.f};
#pragma unroll
  for (int w = 0; w < 4; ++w) {
    unsigned long long mm = masks[w];
    while (mm) {
      int bit = __ffsll(mm) - 1;
      mm &= mm - 1;
      int r = w * 64 + bit;
      float v = tval[b * 256 + r];
      const float4 ov = *(const float4*)&Obuf[((size_t)b * NE + (r >> 3)) * ND + t * 4];
      acc.x += v * ov.x; acc.y += v * ov.y; acc.z += v * ov.z; acc.w += v * ov.w;
    }
  }
  *(float4*)&out[((size_t)b * NS + s) * ND + t * 4] = acc;
}

// ---------------------------------------------------------------------------
extern "C" void kernel_launch(void* const* d_in, const int* in_sizes, int n_in,
                              void* d_out, int out_size, void* d_ws, size_t ws_size,
                              hipStream_t stream) {
  const float* x  = (const float*)d_in[0];
  const float* gw = (const float*)d_in[1];
  const float* w1 = (const float*)d_in[3];
  const float* w2 = (const float*)d_in[4];
  float* out = (float*)d_out;

  char* ws = (char*)d_ws;
  float* logitsT      = (float*)ws;                          // 16,777,216 B
  float* tval         = (float*)(ws + 16777216);             //     65,536 B
  int*   tidx         = (int*)  (ws + 16842752);             //     65,536 B
  unsigned short* A1h = (unsigned short*)(ws + 16908288);    //  4,194,304 B
  unsigned short* A1l = (unsigned short*)(ws + 21102592);    //  4,194,304 B
  unsigned short* Hh  = (unsigned short*)(ws + 25296896);    // 16,777,216 B
  unsigned short* Hl  = (unsigned short*)(ws + 42074112);    // 16,777,216 B
  float* Obuf         = (float*)(ws + 58851328);             //  8,388,608 B

  k_gate_mfma<<<dim3(NS / 128, NB), 256, 0, stream>>>(x, gw, logitsT);
  k_topk<<<NB * NE, 64, 0, stream>>>(logitsT, x, gw, tval, tidx);
  k_merge<<<NB * NE, 256, 0, stream>>>(x, tval, tidx, A1h, A1l);
  k_ffn_mfma<ND, NH, true ><<<dim3(NH / 128, NE), 256, 0, stream>>>(A1h, A1l, w1, Hh, Hl, nullptr);
  k_ffn_mfma<NH, ND, false><<<dim3(ND / 128, NE), 256, 0, stream>>>(Hh, Hl, w2, nullptr, nullptr, Obuf);
  k_scatter<<<dim3(NS, NB), 256, 0, stream>>>(Obuf, tval, tidx, out);
}

// Round 4
// 705.578 us; speedup vs baseline: 1.1124x; 1.1124x over previous
//
#include <hip/hip_runtime.h>
#include <hip/hip_bf16.h>
#include <math.h>

constexpr int NB = 64;     // batch
constexpr int NS = 2048;   // tokens
constexpr int ND = 1024;   // model dim
constexpr int NE = 32;     // experts
constexpr int NH = 4096;   // hidden
constexpr int NK = 8;      // top-k tokens per expert

typedef short bf16x8 __attribute__((ext_vector_type(8)));
typedef float f32x4  __attribute__((ext_vector_type(4)));

// fp32 -> (hi, lo) bf16 split. hi = trunc(v) (1 op); lo = RNE(v - hi).
// Combined error ~2^-17 relative — far below the 1.28e-4 threshold.
__device__ __forceinline__ unsigned short f2bf_rne(float v) {
  unsigned u = __builtin_bit_cast(unsigned, v);
  u += 0x7fffu + ((u >> 16) & 1u);
  return (unsigned short)(u >> 16);
}
__device__ __forceinline__ void split2(float v, unsigned short& h, unsigned short& l) {
  unsigned u = __builtin_bit_cast(unsigned, v);
  h = (unsigned short)(u >> 16);
  float fh = __builtin_bit_cast(float, u & 0xffff0000u);
  l = f2bf_rne(v - fh);
}

// bank swizzles: granule = 16B (8 bf16). Row-varying XOR so lanes reading the
// same k-run across rows land in different bank-quads.
__device__ __forceinline__ int swzB(int n) { return (n & 7) ^ ((n >> 3) & 3); }

__device__ __forceinline__ void gload_lds16(const void* g, void* l) {
  __builtin_amdgcn_global_load_lds(
      (const __attribute__((address_space(1))) unsigned*)g,
      (__attribute__((address_space(3))) unsigned*)l, 16, 0, 0);
}

// ---------------------------------------------------------------------------
// Kernel 1: gating GEMM via split-bf16 MFMA (approx logits, ~1e-5).
// Exact selection restored by the fp64 recheck in k_topk.
// ---------------------------------------------------------------------------
__global__ __launch_bounds__(256) void k_gate_mfma(const float* __restrict__ x,
                                                   const float* __restrict__ gw,
                                                   float* __restrict__ logitsT) {
  const int b  = blockIdx.y;
  const int s0 = blockIdx.x * 128;
  const int t  = threadIdx.x;
  const int l  = t & 63;
  const int w  = t >> 6;

  __shared__ char smem[40960];
  short* Ah = (short*)smem;            // [128][64] swz bf16 hi, 16KB
  short* Al = (short*)(smem + 16384);  // lo, 16KB
  short* Bh = (short*)(smem + 32768);  // [32][64] swz, 4KB
  short* Bl = (short*)(smem + 36864);  // 4KB
  float* trans = (float*)smem;         // [128][33] f32 epilogue (reuses Ah/Al)

  f32x4 acc[2][2] = {};

  const int xr_ = t >> 4, xc = (t & 15) * 4;   // x staging: 16 thr/row
  const int ge = t >> 3,  gk = (t & 7) * 8;    // gw staging: 8 thr/row

  float xreg[8][4];
  float wreg[8];

  auto issue = [&](int k0) {
#pragma unroll
    for (int p = 0; p < 8; ++p) {
      const int r = p * 16 + xr_;
      *(float4*)xreg[p] = *(const float4*)&x[((size_t)b * NS + s0 + r) * ND + k0 + xc];
    }
    *(float4*)&wreg[0] = *(const float4*)&gw[(size_t)ge * ND + k0 + gk];
    *(float4*)&wreg[4] = *(const float4*)&gw[(size_t)ge * ND + k0 + gk + 4];
  };
  auto commit = [&]() {
#pragma unroll
    for (int p = 0; p < 8; ++p) {
      const int r = p * 16 + xr_;
      unsigned short h[4], lo[4];
#pragma unroll
      for (int j = 0; j < 4; ++j) split2(xreg[p][j], h[j], lo[j]);
      const int off = r * 64 + (xc ^ ((r & 7) * 8));
      *(ushort4*)&Ah[off] = make_ushort4(h[0], h[1], h[2], h[3]);
      *(ushort4*)&Al[off] = make_ushort4(lo[0], lo[1], lo[2], lo[3]);
    }
    unsigned short h8[8], l8[8];
#pragma unroll
    for (int j = 0; j < 8; ++j) split2(wreg[j], h8[j], l8[j]);
    const int boff = ge * 64 + (gk ^ ((ge & 7) * 8));
    *(uint4*)&Bh[boff] = *(const uint4*)h8;
    *(uint4*)&Bl[boff] = *(const uint4*)l8;
  };

  issue(0);
  for (int k0 = 0; k0 < ND; k0 += 64) {
    commit();
    __syncthreads();
    if (k0 + 64 < ND) issue(k0 + 64);
#pragma unroll
    for (int ks = 0; ks < 2; ++ks) {
      const int koff = ks * 32 + (l >> 4) * 8;
      bf16x8 ah[2], alo[2], bh[2], blo[2];
#pragma unroll
      for (int mf = 0; mf < 2; ++mf) {
        const int r   = w * 32 + mf * 16 + (l & 15);
        const int off = r * 64 + (koff ^ ((r & 7) * 8));
        ah[mf]  = *(const bf16x8*)&Ah[off];
        alo[mf] = *(const bf16x8*)&Al[off];
      }
#pragma unroll
      for (int nf = 0; nf < 2; ++nf) {
        const int n   = nf * 16 + (l & 15);
        const int off = n * 64 + (koff ^ ((n & 7) * 8));
        bh[nf]  = *(const bf16x8*)&Bh[off];
        blo[nf] = *(const bf16x8*)&Bl[off];
      }
#pragma unroll
      for (int mf = 0; mf < 2; ++mf)
#pragma unroll
        for (int nf = 0; nf < 2; ++nf) {
          acc[mf][nf] = __builtin_amdgcn_mfma_f32_16x16x32_bf16(ah[mf],  bh[nf],  acc[mf][nf], 0, 0, 0);
          acc[mf][nf] = __builtin_amdgcn_mfma_f32_16x16x32_bf16(alo[mf], bh[nf],  acc[mf][nf], 0, 0, 0);
          acc[mf][nf] = __builtin_amdgcn_mfma_f32_16x16x32_bf16(ah[mf],  blo[nf], acc[mf][nf], 0, 0, 0);
        }
    }
    __syncthreads();
  }
  // transpose epilogue through LDS for coalesced [e][s] stores
#pragma unroll
  for (int mf = 0; mf < 2; ++mf)
#pragma unroll
    for (int nf = 0; nf < 2; ++nf)
#pragma unroll
      for (int j = 0; j < 4; ++j) {
        const int sl = w * 32 + mf * 16 + (l >> 4) * 4 + j;
        const int ec = nf * 16 + (l & 15);
        trans[sl * 33 + ec] = acc[mf][nf][j];
      }
  __syncthreads();
  const int eo = t >> 3, sc = (t & 7) * 16;
#pragma unroll
  for (int j4 = 0; j4 < 4; ++j4) {
    float4 v;
    v.x = trans[(sc + j4 * 4 + 0) * 33 + eo];
    v.y = trans[(sc + j4 * 4 + 1) * 33 + eo];
    v.z = trans[(sc + j4 * 4 + 2) * 33 + eo];
    v.w = trans[(sc + j4 * 4 + 3) * 33 + eo];
    *(float4*)&logitsT[((size_t)b * NE + eo) * NS + s0 + sc + j4 * 4] = v;
  }
}

// ---------------------------------------------------------------------------
// Kernel 2: approx top-16 + softmax denom, then exact fp64 recheck of the 16
// candidates -> exact top-8 ordering. One wave per (b,e).
// ---------------------------------------------------------------------------
__global__ __launch_bounds__(64) void k_topk(const float* __restrict__ logitsT,
                                             const float* __restrict__ x,
                                             const float* __restrict__ gw,
                                             float* __restrict__ tval,
                                             int* __restrict__ tidx) {
  const int be = blockIdx.x;
  const int b = be >> 5, e = be & 31;
  const float* row = logitsT + (size_t)be * NS;
  const int lane = threadIdx.x;

  float p8[8]; int i8[8];
#pragma unroll
  for (int j = 0; j < 8; ++j) { p8[j] = -INFINITY; i8[j] = 0x7fffffff; }
  float mx = -INFINITY;
  for (int s = lane; s < NS; s += 64) {
    float lv = row[s];
    mx = fmaxf(mx, lv);
    if (lv > p8[0] || (lv == p8[0] && s < i8[0])) {
      int pos = 0;
#pragma unroll
      for (int j = 1; j < 8; ++j) {
        if (lv > p8[j] || (lv == p8[j] && s < i8[j])) {
          p8[j - 1] = p8[j]; i8[j - 1] = i8[j]; pos = j;
        } else break;
      }
      p8[pos] = lv; i8[pos] = s;
    }
  }
#pragma unroll
  for (int off = 32; off; off >>= 1) mx = fmaxf(mx, __shfl_xor(mx, off));
  double sum = 0.0;
  for (int s = lane; s < NS; s += 64) sum += (double)expf(row[s] - mx);
#pragma unroll
  for (int off = 32; off; off >>= 1) sum += __shfl_xor(sum, off);
  const double inv = 1.0 / sum;

  int ci[16];
  int ptr = 7;
#pragma unroll
  for (int r = 0; r < 16; ++r) {
    float bp = (ptr >= 0) ? p8[ptr] : -INFINITY;
    int   bi = (ptr >= 0) ? i8[ptr] : 0x7fffffff;
    int   bl = lane;
#pragma unroll
    for (int off = 1; off < 64; off <<= 1) {
      float op = __shfl_xor(bp, off);
      int   oi = __shfl_xor(bi, off);
      int   ol = __shfl_xor(bl, off);
      if (op > bp || (op == bp && oi < bi)) { bp = op; bi = oi; bl = ol; }
    }
    ci[r] = bi;
    if (lane == bl) ptr--;
  }

  const int kb = lane * 16;
  float gwl[16];
  *(float4*)&gwl[0]  = *(const float4*)&gw[(size_t)e * ND + kb + 0];
  *(float4*)&gwl[4]  = *(const float4*)&gw[(size_t)e * ND + kb + 4];
  *(float4*)&gwl[8]  = *(const float4*)&gw[(size_t)e * ND + kb + 8];
  *(float4*)&gwl[12] = *(const float4*)&gw[(size_t)e * ND + kb + 12];
  float lc[16];
#pragma unroll
  for (int c = 0; c < 16; ++c) {
    const float* xr2 = x + ((size_t)b * NS + ci[c]) * ND + kb;
    float xv[16];
    *(float4*)&xv[0]  = *(const float4*)&xr2[0];
    *(float4*)&xv[4]  = *(const float4*)&xr2[4];
    *(float4*)&xv[8]  = *(const float4*)&xr2[8];
    *(float4*)&xv[12] = *(const float4*)&xr2[12];
    double d = 0.0;
#pragma unroll
    for (int j = 0; j < 16; ++j) d += (double)xv[j] * (double)gwl[j];
#pragma unroll
    for (int off = 32; off; off >>= 1) d += __shfl_xor(d, off);
    lc[c] = (float)d;
  }
  int rank[16];
#pragma unroll
  for (int c = 0; c < 16; ++c) {
    int r = 0;
#pragma unroll
    for (int c2 = 0; c2 < 16; ++c2)
      if (c2 != c)
        r += (lc[c2] > lc[c]) || (lc[c2] == lc[c] && ci[c2] < ci[c]);
    rank[c] = r;
  }
  if (lane == 0) {
#pragma unroll
    for (int c = 0; c < 16; ++c)
      if (rank[c] < 8) {
        tval[be * 8 + rank[c]] = (float)((double)expf(lc[c] - mx) * inv);
        tidx[be * 8 + rank[c]] = ci[c];
      }
  }
}

// ---------------------------------------------------------------------------
// Kernel 3: mux/merge -> split-bf16 A as pre-swizzled 64x64 tiles
// [e][kt][ m*64 + ((g ^ (m&7))<<3) + (k&7) ],  g = (k&63)>>3, m = b.
// ---------------------------------------------------------------------------
__global__ __launch_bounds__(256) void k_merge(const float* __restrict__ x,
                                               const float* __restrict__ tval,
                                               const int* __restrict__ tidx,
                                               unsigned short* __restrict__ Ah,
                                               unsigned short* __restrict__ Al) {
  const int be = blockIdx.x;
  const int b  = be >> 5;
  const int e  = be & 31;
  const int t  = threadIdx.x;
  float4 acc = {0.f, 0.f, 0.f, 0.f};
#pragma unroll
  for (int k = 0; k < 8; ++k) {
    float v = tval[be * 8 + k];
    int   s = tidx[be * 8 + k];
    float4 xv = *(const float4*)&x[((size_t)b * NS + s) * ND + t * 4];
    acc.x += v * xv.x; acc.y += v * xv.y; acc.z += v * xv.z; acc.w += v * xv.w;
  }
  unsigned short h[4], lo[4];
  split2(acc.x, h[0], lo[0]); split2(acc.y, h[1], lo[1]);
  split2(acc.z, h[2], lo[2]); split2(acc.w, h[3], lo[3]);
  const int kt = t >> 4;
  const int g  = (t & 15) >> 1;
  const size_t off = ((size_t)(e * 16 + kt)) * 4096 + b * 64 + ((g ^ (b & 7)) << 3) + (t & 1) * 4;
  *(ushort4*)&Ah[off] = make_ushort4(h[0], h[1], h[2], h[3]);
  *(ushort4*)&Al[off] = make_ushort4(lo[0], lo[1], lo[2], lo[3]);
}

// ---------------------------------------------------------------------------
// Kernels 4/5: per-expert FFN GEMM, split-bf16 MFMA.
// A: pre-swizzled 64x64 bf16 tiles staged via global_load_lds (DMA, no VALU).
// W: fp32 float4 row loads -> cheap split -> [n][k] swizzled LDS (b128 writes).
// Epilogue: LDS transpose -> 16B vector stores (swizzled tiles for FFN1's H).
// BN=128: 4 waves 2x2 (32m x 64n). BN=64: 4 waves 4x1 (16m x 64n).
// ---------------------------------------------------------------------------
template <int K, int N, int BN, bool GELU>
__global__ __launch_bounds__(256) void k_ffn(const unsigned short* __restrict__ AhT,
                                             const unsigned short* __restrict__ AlT,
                                             const float* __restrict__ W,
                                             unsigned short* __restrict__ OhT,
                                             unsigned short* __restrict__ OlT,
                                             float* __restrict__ Of) {
  constexpr int KT  = K / 64;
  constexpr int WSH = (BN == 128) ? 1 : 0;   // log2(waves along n)
  constexpr int MF  = (BN == 128) ? 2 : 1;   // m-frags per wave
  constexpr int WM  = MF * 16;               // m rows per wave

  const int e  = blockIdx.y;
  const int n0 = blockIdx.x * BN;
  const int t  = threadIdx.x;
  const int l  = t & 63;
  const int w  = t >> 6;
  const int wc = w & ((1 << WSH) - 1);
  const int wr = w >> WSH;

  __shared__ char smem[16384 + BN * 256];
  short* Ah = (short*)smem;                       // [64][64] swz, 8KB
  short* Al = (short*)(smem + 8192);              // 8KB
  short* Bh = (short*)(smem + 16384);             // [BN][64] swz
  short* Bl = (short*)(smem + 16384 + BN * 128);

  const float* Wbase = W + (size_t)e * (K + 1) * N;
  f32x4 acc[MF][4] = {};

  for (int kt = 0; kt < KT; ++kt) {
    // --- stage A via DMA (in flight across the W conversion below) ---
    {
      const unsigned short* ah = AhT + ((size_t)(e * KT + kt)) * 4096;
      const unsigned short* al = AlT + ((size_t)(e * KT + kt)) * 4096;
#pragma unroll
      for (int i = 0; i < 2; ++i) {
        gload_lds16(ah + i * 2048 + t * 8, Ah + i * 2048 + (t >> 6) * 512);
        gload_lds16(al + i * 2048 + t * 8, Al + i * 2048 + (t >> 6) * 512);
      }
    }
    // --- stage W: float4 row loads, split, transposed swizzled LDS ---
    const int k0 = kt * 64;
    if (BN == 128) {
      const int wn4 = (t & 31) * 4;
      const int wk8 = (t >> 5) * 8;
      const float* Wg = Wbase + (size_t)(k0 + wk8) * N + n0 + wn4;
#pragma unroll
      for (int hf = 0; hf < 2; ++hf) {
        float4 r[4];
#pragma unroll
        for (int i = 0; i < 4; ++i) r[i] = *(const float4*)&Wg[(size_t)(hf * 4 + i) * N];
#pragma unroll
        for (int u = 0; u < 4; ++u) {
          const int n = wn4 + u;
          unsigned short hh[4], ll[4];
          split2(((const float*)&r[0])[u], hh[0], ll[0]);
          split2(((const float*)&r[1])[u], hh[1], ll[1]);
          split2(((const float*)&r[2])[u], hh[2], ll[2]);
          split2(((const float*)&r[3])[u], hh[3], ll[3]);
          const int off = n * 64 + (((wk8 >> 3) ^ swzB(n)) << 3) + hf * 4;
          *(ushort4*)&Bh[off] = *(const ushort4*)hh;
          *(ushort4*)&Bl[off] = *(const ushort4*)ll;
        }
      }
    } else {
      const int nb4 = (t & 15) * 4;
      const int kq  = t >> 4;              // rows kq*4 .. +3
      const float* Wg = Wbase + (size_t)(k0 + kq * 4) * N + n0 + nb4;
      float4 r[4];
#pragma unroll
      for (int i = 0; i < 4; ++i) r[i] = *(const float4*)&Wg[(size_t)i * N];
#pragma unroll
      for (int u = 0; u < 4; ++u) {
        const int n = nb4 + u;
        unsigned short hh[4], ll[4];
        split2(((const float*)&r[0])[u], hh[0], ll[0]);
        split2(((const float*)&r[1])[u], hh[1], ll[1]);
        split2(((const float*)&r[2])[u], hh[2], ll[2]);
        split2(((const float*)&r[3])[u], hh[3], ll[3]);
        const int off = n * 64 + (((kq >> 1) ^ swzB(n)) << 3) + (kq & 1) * 4;
        *(ushort4*)&Bh[off] = *(const ushort4*)hh;
        *(ushort4*)&Bl[off] = *(const ushort4*)ll;
      }
    }
    __syncthreads();
    // --- MFMA phase ---
#pragma unroll
    for (int ks = 0; ks < 2; ++ks) {
      const int gk = ks * 4 + (l >> 4);    // 16B granule of the k-run
      bf16x8 ah[MF], alo[MF], bh[4], blo[4];
#pragma unroll
      for (int mf = 0; mf < MF; ++mf) {
        const int m   = wr * WM + mf * 16 + (l & 15);
        const int off = m * 64 + ((gk ^ (m & 7)) << 3);
        ah[mf]  = *(const bf16x8*)&Ah[off];
        alo[mf] = *(const bf16x8*)&Al[off];
      }
#pragma unroll
      for (int nf = 0; nf < 4; ++nf) {
        const int n   = wc * 64 + nf * 16 + (l & 15);
        const int off = n * 64 + ((gk ^ swzB(n)) << 3);
        bh[nf]  = *(const bf16x8*)&Bh[off];
        blo[nf] = *(const bf16x8*)&Bl[off];
      }
#pragma unroll
      for (int mf = 0; mf < MF; ++mf)
#pragma unroll
        for (int nf = 0; nf < 4; ++nf) {
          acc[mf][nf] = __builtin_amdgcn_mfma_f32_16x16x32_bf16(ah[mf],  bh[nf],  acc[mf][nf], 0, 0, 0);
          acc[mf][nf] = __builtin_amdgcn_mfma_f32_16x16x32_bf16(alo[mf], bh[nf],  acc[mf][nf], 0, 0, 0);
          acc[mf][nf] = __builtin_amdgcn_mfma_f32_16x16x32_bf16(ah[mf],  blo[nf], acc[mf][nf], 0, 0, 0);
        }
    }
    __syncthreads();
  }

  // ---------------- epilogue ----------------
  if (GELU) {
    // +bias, exact GELU, split, pack (hi<<16|lo) into LDS transpose buffer
    unsigned* trans = (unsigned*)smem;  // [64][132]
#pragma unroll
    for (int nf = 0; nf < 4; ++nf) {
      const int cl = wc * 64 + nf * 16 + (l & 15);
      const float bias = Wbase[(size_t)K * N + n0 + cl];
#pragma unroll
      for (int mf = 0; mf < MF; ++mf)
#pragma unroll
        for (int j = 0; j < 4; ++j) {
          const int m = wr * WM + mf * 16 + (l >> 4) * 4 + j;
          float v = acc[mf][nf][j] + bias;
          v = 0.5f * v * (1.0f + erff(v * 0.70710678118654752440f));
          unsigned short h, lo;
          split2(v, h, lo);
          trans[m * 132 + cl] = ((unsigned)h << 16) | lo;
        }
    }
    __syncthreads();
    const int m = t >> 2;
#pragma unroll
    for (int q = 0; q < 4; ++q) {
      const int cl = (t & 3) * 32 + q * 8;
      unsigned w8[8];
      *(uint4*)&w8[0] = *(const uint4*)&trans[m * 132 + cl];
      *(uint4*)&w8[4] = *(const uint4*)&trans[m * 132 + cl + 4];
      unsigned hw[4], lw[4];
#pragma unroll
      for (int p = 0; p < 4; ++p) {
        hw[p] = (w8[2 * p] >> 16) | (w8[2 * p + 1] & 0xffff0000u);
        lw[p] = (w8[2 * p] & 0xffffu) | (w8[2 * p + 1] << 16);
      }
      const int kg  = n0 + cl;
      const int kt2 = kg >> 6, g = (kg & 63) >> 3;
      const size_t off = ((size_t)(e * (N / 64) + kt2)) * 4096 + m * 64 + ((g ^ (m & 7)) << 3);
      *(uint4*)&OhT[off] = *(const uint4*)hw;
      *(uint4*)&OlT[off] = *(const uint4*)lw;
    }
  } else {
    float* transF = (float*)smem;  // [64][68]
#pragma unroll
    for (int nf = 0; nf < 4; ++nf) {
      const int cl = nf * 16 + (l & 15);
      const float bias = Wbase[(size_t)K * N + n0 + cl];
#pragma unroll
      for (int j = 0; j < 4; ++j) {
        const int m = wr * WM + (l >> 4) * 4 + j;
        transF[m * 68 + cl] = acc[0][nf][j] + bias;
      }
    }
    __syncthreads();
    const int m = t >> 2;
#pragma unroll
    for (int q = 0; q < 4; ++q) {
      const int cl = (t & 3) * 16 + q * 4;
      float4 v = *(const float4*)&transF[m * 68 + cl];
      *(float4*)&Of[((size_t)m * NE + e) * ND + n0 + cl] = v;
    }
  }
}

// ---------------------------------------------------------------------------
// Kernel 6: demux/scatter (deterministic, atomic-free, zero-fills).
// ---------------------------------------------------------------------------
__global__ __launch_bounds__(256) void k_scatter(const float* __restrict__ Obuf,
                                                 const float* __restrict__ tval,
                                                 const int* __restrict__ tidx,
                                                 float* __restrict__ out) {
  const int s = blockIdx.x;
  const int b = blockIdx.y;
  const int t = threadIdx.x;
  __shared__ unsigned long long masks[4];

  const int myIdx = tidx[b * 256 + t];
  unsigned long long m = __ballot(myIdx == s);
  if ((t & 63) == 0) masks[t >> 6] = m;
  __syncthreads();

  float4 acc = {0.f, 0.f, 0.f, 0.f};
#pragma unroll
  for (int w = 0; w < 4; ++w) {
    unsigned long long mm = masks[w];
    while (mm) {
      int bit = __ffsll(mm) - 1;
      mm &= mm - 1;
      int r = w * 64 + bit;
      float v = tval[b * 256 + r];
      const float4 ov = *(const float4*)&Obuf[((size_t)b * NE + (r >> 3)) * ND + t * 4];
      acc.x += v * ov.x; acc.y += v * ov.y; acc.z += v * ov.z; acc.w += v * ov.w;
    }
  }
  *(float4*)&out[((size_t)b * NS + s) * ND + t * 4] = acc;
}

// ---------------------------------------------------------------------------
extern "C" void kernel_launch(void* const* d_in, const int* in_sizes, int n_in,
                              void* d_out, int out_size, void* d_ws, size_t ws_size,
                              hipStream_t stream) {
  const float* x  = (const float*)d_in[0];
  const float* gw = (const float*)d_in[1];
  const float* w1 = (const float*)d_in[3];
  const float* w2 = (const float*)d_in[4];
  float* out = (float*)d_out;

  char* ws = (char*)d_ws;
  float* logitsT      = (float*)ws;                          // 16,777,216 B
  float* tval         = (float*)(ws + 16777216);             //     65,536 B
  int*   tidx         = (int*)  (ws + 16842752);             //     65,536 B
  unsigned short* A1h = (unsigned short*)(ws + 16908288);    //  4,194,304 B (tiles)
  unsigned short* A1l = (unsigned short*)(ws + 21102592);    //  4,194,304 B
  unsigned short* Hh  = (unsigned short*)(ws + 25296896);    // 16,777,216 B (tiles)
  unsigned short* Hl  = (unsigned short*)(ws + 42074112);    // 16,777,216 B
  float* Obuf         = (float*)(ws + 58851328);             //  8,388,608 B

  k_gate_mfma<<<dim3(NS / 128, NB), 256, 0, stream>>>(x, gw, logitsT);
  k_topk<<<NB * NE, 64, 0, stream>>>(logitsT, x, gw, tval, tidx);
  k_merge<<<NB * NE, 256, 0, stream>>>(x, tval, tidx, A1h, A1l);
  k_ffn<ND, NH, 128, true ><<<dim3(NH / 128, NE), 256, 0, stream>>>(A1h, A1l, w1, Hh, Hl, nullptr);
  k_ffn<NH, ND, 64, false><<<dim3(ND / 64, NE), 256, 0, stream>>>(Hh, Hl, w2, nullptr, nullptr, Obuf);
  k_scatter<<<dim3(NS, NB), 256, 0, stream>>>(Obuf, tval, tidx, out);
}

// Round 5
// 659.056 us; speedup vs baseline: 1.1909x; 1.0706x over previous
//
#include <hip/hip_runtime.h>
#include <hip/hip_bf16.h>
#include <math.h>

constexpr int NB = 64;     // batch
constexpr int NS = 2048;   // tokens
constexpr int ND = 1024;   // model dim
constexpr int NE = 32;     // experts
constexpr int NH = 4096;   // hidden
constexpr int NK = 8;      // top-k tokens per expert

typedef short bf16x8 __attribute__((ext_vector_type(8)));
typedef float f32x4  __attribute__((ext_vector_type(4)));

// fp32 -> bf16 RNE (4 ops) and fp32 -> (hi=trunc, lo=RNE(residual)) split.
__device__ __forceinline__ unsigned short f2bf_rne(float v) {
  unsigned u = __builtin_bit_cast(unsigned, v);
  u += 0x7fffu + ((u >> 16) & 1u);
  return (unsigned short)(u >> 16);
}
__device__ __forceinline__ void split2(float v, unsigned short& h, unsigned short& l) {
  unsigned u = __builtin_bit_cast(unsigned, v);
  h = (unsigned short)(u >> 16);
  float fh = __builtin_bit_cast(float, u & 0xffff0000u);
  l = f2bf_rne(v - fh);
}

__device__ __forceinline__ void gload_lds16(const void* g, void* l) {
  __builtin_amdgcn_global_load_lds(
      (const __attribute__((address_space(1))) unsigned*)g,
      (__attribute__((address_space(3))) unsigned*)l, 16, 0, 0);
}

// ---------------------------------------------------------------------------
// Kernel 1: gating GEMM via split-bf16 MFMA (approx logits, ~1e-5).
// Exact selection restored by the fp64 recheck in k_topk.
// ---------------------------------------------------------------------------
__global__ __launch_bounds__(256) void k_gate_mfma(const float* __restrict__ x,
                                                   const float* __restrict__ gw,
                                                   float* __restrict__ logitsT) {
  const int b  = blockIdx.y;
  const int s0 = blockIdx.x * 128;
  const int t  = threadIdx.x;
  const int l  = t & 63;
  const int w  = t >> 6;

  __shared__ char smem[40960];
  short* Ah = (short*)smem;            // [128][64] swz bf16 hi, 16KB
  short* Al = (short*)(smem + 16384);  // lo, 16KB
  short* Bh = (short*)(smem + 32768);  // [32][64] swz, 4KB
  short* Bl = (short*)(smem + 36864);  // 4KB
  float* trans = (float*)smem;         // [128][33] f32 epilogue (reuses Ah/Al)

  f32x4 acc[2][2] = {};

  const int xr_ = t >> 4, xc = (t & 15) * 4;   // x staging: 16 thr/row
  const int ge = t >> 3,  gk = (t & 7) * 8;    // gw staging: 8 thr/row

  float xreg[8][4];
  float wreg[8];

  auto issue = [&](int k0) {
#pragma unroll
    for (int p = 0; p < 8; ++p) {
      const int r = p * 16 + xr_;
      *(float4*)xreg[p] = *(const float4*)&x[((size_t)b * NS + s0 + r) * ND + k0 + xc];
    }
    *(float4*)&wreg[0] = *(const float4*)&gw[(size_t)ge * ND + k0 + gk];
    *(float4*)&wreg[4] = *(const float4*)&gw[(size_t)ge * ND + k0 + gk + 4];
  };
  auto commit = [&]() {
#pragma unroll
    for (int p = 0; p < 8; ++p) {
      const int r = p * 16 + xr_;
      unsigned short h[4], lo[4];
#pragma unroll
      for (int j = 0; j < 4; ++j) split2(xreg[p][j], h[j], lo[j]);
      const int off = r * 64 + (xc ^ ((r & 7) * 8));
      *(ushort4*)&Ah[off] = make_ushort4(h[0], h[1], h[2], h[3]);
      *(ushort4*)&Al[off] = make_ushort4(lo[0], lo[1], lo[2], lo[3]);
    }
    unsigned short h8[8], l8[8];
#pragma unroll
    for (int j = 0; j < 8; ++j) split2(wreg[j], h8[j], l8[j]);
    const int boff = ge * 64 + (gk ^ ((ge & 7) * 8));
    *(uint4*)&Bh[boff] = *(const uint4*)h8;
    *(uint4*)&Bl[boff] = *(const uint4*)l8;
  };

  issue(0);
  for (int k0 = 0; k0 < ND; k0 += 64) {
    commit();
    __syncthreads();
    if (k0 + 64 < ND) issue(k0 + 64);
#pragma unroll
    for (int ks = 0; ks < 2; ++ks) {
      const int koff = ks * 32 + (l >> 4) * 8;
      bf16x8 ah[2], alo[2], bh[2], blo[2];
#pragma unroll
      for (int mf = 0; mf < 2; ++mf) {
        const int r   = w * 32 + mf * 16 + (l & 15);
        const int off = r * 64 + (koff ^ ((r & 7) * 8));
        ah[mf]  = *(const bf16x8*)&Ah[off];
        alo[mf] = *(const bf16x8*)&Al[off];
      }
#pragma unroll
      for (int nf = 0; nf < 2; ++nf) {
        const int n   = nf * 16 + (l & 15);
        const int off = n * 64 + (koff ^ ((n & 7) * 8));
        bh[nf]  = *(const bf16x8*)&Bh[off];
        blo[nf] = *(const bf16x8*)&Bl[off];
      }
#pragma unroll
      for (int mf = 0; mf < 2; ++mf)
#pragma unroll
        for (int nf = 0; nf < 2; ++nf) {
          acc[mf][nf] = __builtin_amdgcn_mfma_f32_16x16x32_bf16(ah[mf],  bh[nf],  acc[mf][nf], 0, 0, 0);
          acc[mf][nf] = __builtin_amdgcn_mfma_f32_16x16x32_bf16(alo[mf], bh[nf],  acc[mf][nf], 0, 0, 0);
          acc[mf][nf] = __builtin_amdgcn_mfma_f32_16x16x32_bf16(ah[mf],  blo[nf], acc[mf][nf], 0, 0, 0);
        }
    }
    __syncthreads();
  }
  // transpose epilogue through LDS for coalesced [e][s] stores
#pragma unroll
  for (int mf = 0; mf < 2; ++mf)
#pragma unroll
    for (int nf = 0; nf < 2; ++nf)
#pragma unroll
      for (int j = 0; j < 4; ++j) {
        const int sl = w * 32 + mf * 16 + (l >> 4) * 4 + j;
        const int ec = nf * 16 + (l & 15);
        trans[sl * 33 + ec] = acc[mf][nf][j];
      }
  __syncthreads();
  const int eo = t >> 3, sc = (t & 7) * 16;
#pragma unroll
  for (int j4 = 0; j4 < 4; ++j4) {
    float4 v;
    v.x = trans[(sc + j4 * 4 + 0) * 33 + eo];
    v.y = trans[(sc + j4 * 4 + 1) * 33 + eo];
    v.z = trans[(sc + j4 * 4 + 2) * 33 + eo];
    v.w = trans[(sc + j4 * 4 + 3) * 33 + eo];
    *(float4*)&logitsT[((size_t)b * NE + eo) * NS + s0 + sc + j4 * 4] = v;
  }
}

// ---------------------------------------------------------------------------
// Kernel 2: 4 waves/block, single pass over logitsT. Each lane holds its 8
// logits sorted in registers; per-wave top-16 by argmax-extract; wave-0 merge
// -> global top-16; denom via local-max rescale (no second read); fp64
// recheck of 16 candidates (4/wave) -> exact top-8 ordering.
// ---------------------------------------------------------------------------
__global__ __launch_bounds__(256) void k_topk(const float* __restrict__ logitsT,
                                              const float* __restrict__ x,
                                              const float* __restrict__ gw,
                                              float* __restrict__ tval,
                                              int* __restrict__ tidx) {
  const int be = blockIdx.x, b = be >> 5, e = be & 31;
  const float* row = logitsT + (size_t)be * NS;
  const int t = threadIdx.x, w = t >> 6, lane = t & 63;

  __shared__ float  cv[64];
  __shared__ int    cix[64];
  __shared__ double wsum[4];
  __shared__ float  smax;
  __shared__ int    gci[16];
  __shared__ float  glc[16];
  __shared__ double ginv;

  float v[8]; int si[8];
#pragma unroll
  for (int j = 0; j < 8; ++j) {
    const int s = w * 512 + lane + j * 64;
    v[j] = row[s]; si[j] = s;
  }
  // sort desc (ties: lower idx first) — static-index bubble network
#pragma unroll
  for (int i = 0; i < 7; ++i)
#pragma unroll
    for (int j = 0; j < 7 - i; ++j) {
      const bool sw = (v[j + 1] > v[j]) || (v[j + 1] == v[j] && si[j + 1] < si[j]);
      const float tv = sw ? v[j + 1] : v[j];
      const int   ti = sw ? si[j + 1] : si[j];
      v[j + 1] = sw ? v[j] : v[j + 1];  si[j + 1] = sw ? si[j] : si[j + 1];
      v[j] = tv;  si[j] = ti;
    }
  const float mxl = v[0];
  double s8 = 1.0;
#pragma unroll
  for (int j = 1; j < 8; ++j) s8 += (double)expf(v[j] - mxl);

  // per-wave top-16 (pop-head extraction)
  for (int r = 0; r < 16; ++r) {
    float bp = v[0]; int bi = si[0]; int bl = lane;
#pragma unroll
    for (int off = 1; off < 64; off <<= 1) {
      const float op = __shfl_xor(bp, off);
      const int   oi = __shfl_xor(bi, off);
      const int   ol = __shfl_xor(bl, off);
      if (op > bp || (op == bp && oi < bi)) { bp = op; bi = oi; bl = ol; }
    }
    if (lane == 0) { cv[w * 16 + r] = bp; cix[w * 16 + r] = bi; }
    if (lane == bl) {
      v[0]=v[1]; v[1]=v[2]; v[2]=v[3]; v[3]=v[4]; v[4]=v[5]; v[5]=v[6]; v[6]=v[7]; v[7]=-INFINITY;
      si[0]=si[1]; si[1]=si[2]; si[2]=si[3]; si[3]=si[4]; si[4]=si[5]; si[5]=si[6]; si[6]=si[7]; si[7]=0x7fffffff;
    }
  }
  __syncthreads();
  // wave 0 merges 64 candidates -> global top-16
  if (w == 0) {
    float mv = cv[lane]; int mi = cix[lane];
    for (int r = 0; r < 16; ++r) {
      float bp = mv; int bi = mi; int bl = lane;
#pragma unroll
      for (int off = 1; off < 64; off <<= 1) {
        const float op = __shfl_xor(bp, off);
        const int   oi = __shfl_xor(bi, off);
        const int   ol = __shfl_xor(bl, off);
        if (op > bp || (op == bp && oi < bi)) { bp = op; bi = oi; bl = ol; }
      }
      if (lane == 0) { gci[r] = bi; if (r == 0) smax = bp; }
      if (lane == bl) { mv = -INFINITY; mi = 0x7fffffff; }
    }
  }
  __syncthreads();
  const float mx = smax;
  double lsum = s8 * (double)expf(mxl - mx);
#pragma unroll
  for (int off = 32; off; off >>= 1) lsum += __shfl_xor(lsum, off);
  if (lane == 0) wsum[w] = lsum;
  __syncthreads();
  if (t == 0) ginv = 1.0 / (wsum[0] + wsum[1] + wsum[2] + wsum[3]);

  // fp64 recheck: wave w -> candidates 4w..4w+3
  const int kb = lane * 16;
  float gwl[16];
  *(float4*)&gwl[0]  = *(const float4*)&gw[(size_t)e * ND + kb];
  *(float4*)&gwl[4]  = *(const float4*)&gw[(size_t)e * ND + kb + 4];
  *(float4*)&gwl[8]  = *(const float4*)&gw[(size_t)e * ND + kb + 8];
  *(float4*)&gwl[12] = *(const float4*)&gw[(size_t)e * ND + kb + 12];
#pragma unroll
  for (int q = 0; q < 4; ++q) {
    const int c = w * 4 + q;
    const int ciq = gci[c];
    const float* xr = x + ((size_t)b * NS + ciq) * ND + kb;
    float xv[16];
    *(float4*)&xv[0]  = *(const float4*)&xr[0];
    *(float4*)&xv[4]  = *(const float4*)&xr[4];
    *(float4*)&xv[8]  = *(const float4*)&xr[8];
    *(float4*)&xv[12] = *(const float4*)&xr[12];
    double d = 0.0;
#pragma unroll
    for (int j2 = 0; j2 < 16; ++j2) d += (double)xv[j2] * (double)gwl[j2];
#pragma unroll
    for (int off = 32; off; off >>= 1) d += __shfl_xor(d, off);
    if (lane == 0) glc[c] = (float)d;
  }
  __syncthreads();
  if (t < 16) {
    const float mylc = glc[t]; const int myci = gci[t];
    int rank = 0;
#pragma unroll
    for (int c2 = 0; c2 < 16; ++c2) {
      if (c2 == t) continue;
      rank += (glc[c2] > mylc) || (glc[c2] == mylc && gci[c2] < myci);
    }
    if (rank < 8) {
      tval[be * 8 + rank] = (float)((double)expf(mylc - mx) * ginv);
      tidx[be * 8 + rank] = myci;
    }
  }
}

// ---------------------------------------------------------------------------
// Kernel 3: mux/merge -> split-bf16 A as pre-swizzled 64x64 tiles
// [e][kt][ m*64 + ((g ^ (m&7))<<3) + (k&7) ],  g = (k&63)>>3, m = b.
// ---------------------------------------------------------------------------
__global__ __launch_bounds__(256) void k_merge(const float* __restrict__ x,
                                               const float* __restrict__ tval,
                                               const int* __restrict__ tidx,
                                               unsigned short* __restrict__ Ah,
                                               unsigned short* __restrict__ Al) {
  const int be = blockIdx.x;
  const int b  = be >> 5;
  const int e  = be & 31;
  const int t  = threadIdx.x;
  float4 acc = {0.f, 0.f, 0.f, 0.f};
#pragma unroll
  for (int k = 0; k < 8; ++k) {
    float v = tval[be * 8 + k];
    int   s = tidx[be * 8 + k];
    float4 xv = *(const float4*)&x[((size_t)b * NS + s) * ND + t * 4];
    acc.x += v * xv.x; acc.y += v * xv.y; acc.z += v * xv.z; acc.w += v * xv.w;
  }
  unsigned short h[4], lo[4];
  split2(acc.x, h[0], lo[0]); split2(acc.y, h[1], lo[1]);
  split2(acc.z, h[2], lo[2]); split2(acc.w, h[3], lo[3]);
  const int kt = t >> 4;
  const int g  = (t & 15) >> 1;
  const size_t off = ((size_t)(e * 16 + kt)) * 4096 + b * 64 + ((g ^ (b & 7)) << 3) + (t & 1) * 4;
  *(ushort4*)&Ah[off] = make_ushort4(h[0], h[1], h[2], h[3]);
  *(ushort4*)&Al[off] = make_ushort4(lo[0], lo[1], lo[2], lo[3]);
}

// ---------------------------------------------------------------------------
// Kernels 4/5: per-expert FFN GEMM, 2-term split MFMA (A split hi/lo, W bf16
// RNE). T3 2-phase pipeline, ONE barrier per K-tile:
//   A: global_load_lds DMA from pre-swizzled tiles, LDS double-buffered.
//   W: column-run register prefetch (lane=n, 8 k per run; coalesced 256B/instr)
//      issued one tile ahead; convert+ds_write_b128 after the MFMA phase.
// Waves 2x2: per-wave 32m x (BN/2)n. BN=64 (FFN1), BN=32 (FFN2).
// ---------------------------------------------------------------------------
template <int K, int N, int BN, bool GELU>
__global__ __launch_bounds__(256) void k_ffn(const unsigned short* __restrict__ AhT,
                                             const unsigned short* __restrict__ AlT,
                                             const float* __restrict__ W,
                                             unsigned short* __restrict__ OhT,
                                             unsigned short* __restrict__ OlT,
                                             float* __restrict__ Of) {
  constexpr int KT   = K / 64;
  constexpr int NF   = BN / 32;            // n-frags per wave
  constexpr int NRUN = BN / 32;            // W k-runs per thread
  constexpr int KSTRIDE = (256 / BN) * 8;  // k distance between a thread's runs

  const int e  = blockIdx.y;
  const int n0 = blockIdx.x * BN;
  const int t  = threadIdx.x, l = t & 63, w = t >> 6;
  const int wr = w >> 1, wc = w & 1;

  __shared__ char smem[32768 + 2 * BN * 128];
  // A buf d: smem + d*16384 (hi 8KB @0, lo 8KB @8192). B buf d: smem + 32768 + d*BN*128.

  const float* Wbase = W + (size_t)e * (K + 1) * N;
  f32x4 acc[2][NF] = {};

  const int wn  = t % BN;
  const int wk0 = (t / BN) * 8;
  float wreg[NRUN][8];

  auto issueW = [&](int kt) {
    const float* Wg = Wbase + (size_t)(kt * 64) * N + n0 + wn;
#pragma unroll
    for (int rn = 0; rn < NRUN; ++rn)
#pragma unroll
      for (int j = 0; j < 8; ++j)
        wreg[rn][j] = Wg[(size_t)(wk0 + rn * KSTRIDE + j) * N];
  };
  auto issueA = [&](int kt, int dst) {
    const unsigned short* ah = AhT + ((size_t)(e * KT + kt)) * 4096;
    const unsigned short* al = AlT + ((size_t)(e * KT + kt)) * 4096;
    char* Ab = smem + dst * 16384;
#pragma unroll
    for (int p = 0; p < 2; ++p) {
      gload_lds16(ah + p * 2048 + t * 8, Ab + p * 4096 + w * 1024);
      gload_lds16(al + p * 2048 + t * 8, Ab + 8192 + p * 4096 + w * 1024);
    }
  };
  auto commitW = [&](int dst) {
    short* Bb = (short*)(smem + 32768 + dst * BN * 128);
#pragma unroll
    for (int rn = 0; rn < NRUN; ++rn) {
      const int kr = (wk0 + rn * KSTRIDE) >> 3;
      unsigned short s8[8];
#pragma unroll
      for (int j = 0; j < 8; ++j) s8[j] = f2bf_rne(wreg[rn][j]);
      *(uint4*)&Bb[wn * 64 + ((kr ^ (wn & 7)) << 3)] = *(const uint4*)s8;
    }
  };
  auto mfma_phase = [&](int cur) {
    const short* Ab = (const short*)(smem + cur * 16384);
    const short* Bb = (const short*)(smem + 32768 + cur * BN * 128);
#pragma unroll
    for (int ks = 0; ks < 2; ++ks) {
      const int g8 = ks * 4 + (l >> 4);
      bf16x8 ah[2], alo[2], bh[NF];
#pragma unroll
      for (int mf = 0; mf < 2; ++mf) {
        const int m   = wr * 32 + mf * 16 + (l & 15);
        const int off = m * 64 + ((g8 ^ (m & 7)) << 3);
        ah[mf]  = *(const bf16x8*)&Ab[off];
        alo[mf] = *(const bf16x8*)&Ab[4096 + off];
      }
#pragma unroll
      for (int nf = 0; nf < NF; ++nf) {
        const int n = wc * (NF * 16) + nf * 16 + (l & 15);
        bh[nf] = *(const bf16x8*)&Bb[n * 64 + ((g8 ^ (n & 7)) << 3)];
      }
#pragma unroll
      for (int mf = 0; mf < 2; ++mf)
#pragma unroll
        for (int nf = 0; nf < NF; ++nf) {
          acc[mf][nf] = __builtin_amdgcn_mfma_f32_16x16x32_bf16(ah[mf],  bh[nf], acc[mf][nf], 0, 0, 0);
          acc[mf][nf] = __builtin_amdgcn_mfma_f32_16x16x32_bf16(alo[mf], bh[nf], acc[mf][nf], 0, 0, 0);
        }
    }
  };

  // prologue
  issueW(0); issueA(0, 0);
  commitW(0);
  __syncthreads();
  if (KT > 1) { issueW(1); issueA(1, 1); }
  int cur = 0;
  for (int kt = 0; kt < KT; ++kt) {
    mfma_phase(cur);
    if (kt + 1 < KT) {
      commitW(cur ^ 1);
      __syncthreads();
      if (kt + 2 < KT) { issueW(kt + 2); issueA(kt + 2, cur); }
      cur ^= 1;
    }
  }
  __syncthreads();

  // ---------------- epilogue ----------------
  if (GELU) {
    unsigned* trans = (unsigned*)smem;  // [64][68] packed (hi<<16 | lo)
#pragma unroll
    for (int nf = 0; nf < NF; ++nf) {
      const int c = wc * (NF * 16) + nf * 16 + (l & 15);
      const float bias = Wbase[(size_t)K * N + n0 + c];
#pragma unroll
      for (int mf = 0; mf < 2; ++mf)
#pragma unroll
        for (int j = 0; j < 4; ++j) {
          const int m = wr * 32 + mf * 16 + (l >> 4) * 4 + j;
          float vv = acc[mf][nf][j] + bias;
          vv = 0.5f * vv * (1.0f + erff(vv * 0.70710678118654752440f));
          unsigned short h, lo;
          split2(vv, h, lo);
          trans[m * 68 + c] = ((unsigned)h << 16) | lo;
        }
    }
    __syncthreads();
    const int m = t >> 2;
    const size_t tb = ((size_t)(e * (N / 64) + blockIdx.x)) * 4096;
#pragma unroll
    for (int sub = 0; sub < 2; ++sub) {
      const int c0 = (t & 3) * 16 + sub * 8;
      unsigned w8[8];
      *(uint4*)&w8[0] = *(const uint4*)&trans[m * 68 + c0];
      *(uint4*)&w8[4] = *(const uint4*)&trans[m * 68 + c0 + 4];
      unsigned hw[4], lw[4];
#pragma unroll
      for (int p = 0; p < 4; ++p) {
        hw[p] = (w8[2 * p] >> 16) | (w8[2 * p + 1] & 0xffff0000u);
        lw[p] = (w8[2 * p] & 0xffffu) | (w8[2 * p + 1] << 16);
      }
      const int g = c0 >> 3;
      const size_t off = tb + m * 64 + ((g ^ (m & 7)) << 3);
      *(uint4*)&OhT[off] = *(const uint4*)hw;
      *(uint4*)&OlT[off] = *(const uint4*)lw;
    }
  } else {
    float* transF = (float*)smem;  // [64][36]
    {
      const int c = wc * 16 + (l & 15);
      const float bias = Wbase[(size_t)K * N + n0 + c];
#pragma unroll
      for (int mf = 0; mf < 2; ++mf)
#pragma unroll
        for (int j = 0; j < 4; ++j) {
          const int m = wr * 32 + mf * 16 + (l >> 4) * 4 + j;
          transF[m * 36 + c] = acc[mf][0][j] + bias;
        }
    }
    __syncthreads();
    const int m = t >> 2;
    const int c0 = (t & 3) * 8;
    float4 v0 = *(const float4*)&transF[m * 36 + c0];
    float4 v1 = *(const float4*)&transF[m * 36 + c0 + 4];
    float* og = Of + ((size_t)m * NE + e) * ND + n0 + c0;
    *(float4*)&og[0] = v0;
    *(float4*)&og[4] = v1;
  }
}

// ---------------------------------------------------------------------------
// Kernel 6: demux/scatter (deterministic, atomic-free, zero-fills).
// ---------------------------------------------------------------------------
__global__ __launch_bounds__(256) void k_scatter(const float* __restrict__ Obuf,
                                                 const float* __restrict__ tval,
                                                 const int* __restrict__ tidx,
                                                 float* __restrict__ out) {
  const int s = blockIdx.x;
  const int b = blockIdx.y;
  const int t = threadIdx.x;
  __shared__ unsigned long long masks[4];

  const int myIdx = tidx[b * 256 + t];
  unsigned long long m = __ballot(myIdx == s);
  if ((t & 63) == 0) masks[t >> 6] = m;
  __syncthreads();

  float4 acc = {0.f, 0.f, 0.f, 0.f};
#pragma unroll
  for (int w = 0; w < 4; ++w) {
    unsigned long long mm = masks[w];
    while (mm) {
      int bit = __ffsll(mm) - 1;
      mm &= mm - 1;
      int r = w * 64 + bit;
      float v = tval[b * 256 + r];
      const float4 ov = *(const float4*)&Obuf[((size_t)b * NE + (r >> 3)) * ND + t * 4];
      acc.x += v * ov.x; acc.y += v * ov.y; acc.z += v * ov.z; acc.w += v * ov.w;
    }
  }
  *(float4*)&out[((size_t)b * NS + s) * ND + t * 4] = acc;
}

// ---------------------------------------------------------------------------
extern "C" void kernel_launch(void* const* d_in, const int* in_sizes, int n_in,
                              void* d_out, int out_size, void* d_ws, size_t ws_size,
                              hipStream_t stream) {
  const float* x  = (const float*)d_in[0];
  const float* gw = (const float*)d_in[1];
  const float* w1 = (const float*)d_in[3];
  const float* w2 = (const float*)d_in[4];
  float* out = (float*)d_out;

  char* ws = (char*)d_ws;
  float* logitsT      = (float*)ws;                          // 16,777,216 B
  float* tval         = (float*)(ws + 16777216);             //     65,536 B
  int*   tidx         = (int*)  (ws + 16842752);             //     65,536 B
  unsigned short* A1h = (unsigned short*)(ws + 16908288);    //  4,194,304 B (tiles)
  unsigned short* A1l = (unsigned short*)(ws + 21102592);    //  4,194,304 B
  unsigned short* Hh  = (unsigned short*)(ws + 25296896);    // 16,777,216 B (tiles)
  unsigned short* Hl  = (unsigned short*)(ws + 42074112);    // 16,777,216 B
  float* Obuf         = (float*)(ws + 58851328);             //  8,388,608 B

  k_gate_mfma<<<dim3(NS / 128, NB), 256, 0, stream>>>(x, gw, logitsT);
  k_topk<<<NB * NE, 256, 0, stream>>>(logitsT, x, gw, tval, tidx);
  k_merge<<<NB * NE, 256, 0, stream>>>(x, tval, tidx, A1h, A1l);
  k_ffn<ND, NH, 64, true ><<<dim3(NH / 64, NE), 256, 0, stream>>>(A1h, A1l, w1, Hh, Hl, nullptr);
  k_ffn<NH, ND, 32, false><<<dim3(ND / 32, NE), 256, 0, stream>>>(Hh, Hl, w2, nullptr, nullptr, Obuf);
  k_scatter<<<dim3(NS, NB), 256, 0, stream>>>(Obuf, tval, tidx, out);
}

// Round 6
// 587.888 us; speedup vs baseline: 1.3351x; 1.1211x over previous
//
#include <hip/hip_runtime.h>
#include <hip/hip_bf16.h>
#include <math.h>

constexpr int NB = 64;     // batch
constexpr int NS = 2048;   // tokens
constexpr int ND = 1024;   // model dim
constexpr int NE = 32;     // experts
constexpr int NH = 4096;   // hidden
constexpr int NK = 8;      // top-k tokens per expert

typedef short bf16x8 __attribute__((ext_vector_type(8)));
typedef float f32x4  __attribute__((ext_vector_type(4)));

// fp32 -> bf16 RNE and fp32 -> (hi=trunc, lo=RNE(residual)) split.
__device__ __forceinline__ unsigned short f2bf_rne(float v) {
  unsigned u = __builtin_bit_cast(unsigned, v);
  u += 0x7fffu + ((u >> 16) & 1u);
  return (unsigned short)(u >> 16);
}
__device__ __forceinline__ void split2(float v, unsigned short& h, unsigned short& l) {
  unsigned u = __builtin_bit_cast(unsigned, v);
  h = (unsigned short)(u >> 16);
  float fh = __builtin_bit_cast(float, u & 0xffff0000u);
  l = f2bf_rne(v - fh);
}

__device__ __forceinline__ void gload_lds16(const void* g, void* l) {
  __builtin_amdgcn_global_load_lds(
      (const __attribute__((address_space(1))) unsigned*)g,
      (__attribute__((address_space(3))) unsigned*)l, 16, 0, 0);
}

// ---------------------------------------------------------------------------
// Kernel 1: gating GEMM via split-bf16 MFMA (3-term; logit err ~1e-6).
// Exact selection restored by the fp64 recheck in k_topk.
// ---------------------------------------------------------------------------
__global__ __launch_bounds__(256) void k_gate_mfma(const float* __restrict__ x,
                                                   const float* __restrict__ gw,
                                                   float* __restrict__ logitsT) {
  const int b  = blockIdx.y;
  const int s0 = blockIdx.x * 128;
  const int t  = threadIdx.x;
  const int l  = t & 63;
  const int w  = t >> 6;

  __shared__ char smem[40960];
  short* Ah = (short*)smem;            // [128][64] swz bf16 hi, 16KB
  short* Al = (short*)(smem + 16384);  // lo, 16KB
  short* Bh = (short*)(smem + 32768);  // [32][64] swz, 4KB
  short* Bl = (short*)(smem + 36864);  // 4KB
  float* trans = (float*)smem;         // [128][33] f32 epilogue (reuses Ah/Al)

  f32x4 acc[2][2] = {};

  const int xr_ = t >> 4, xc = (t & 15) * 4;   // x staging: 16 thr/row
  const int ge = t >> 3,  gk = (t & 7) * 8;    // gw staging: 8 thr/row

  float xreg[8][4];
  float wreg[8];

  auto issue = [&](int k0) {
#pragma unroll
    for (int p = 0; p < 8; ++p) {
      const int r = p * 16 + xr_;
      *(float4*)xreg[p] = *(const float4*)&x[((size_t)b * NS + s0 + r) * ND + k0 + xc];
    }
    *(float4*)&wreg[0] = *(const float4*)&gw[(size_t)ge * ND + k0 + gk];
    *(float4*)&wreg[4] = *(const float4*)&gw[(size_t)ge * ND + k0 + gk + 4];
  };
  auto commit = [&]() {
#pragma unroll
    for (int p = 0; p < 8; ++p) {
      const int r = p * 16 + xr_;
      unsigned short h[4], lo[4];
#pragma unroll
      for (int j = 0; j < 4; ++j) split2(xreg[p][j], h[j], lo[j]);
      const int off = r * 64 + (xc ^ ((r & 7) * 8));
      *(ushort4*)&Ah[off] = make_ushort4(h[0], h[1], h[2], h[3]);
      *(ushort4*)&Al[off] = make_ushort4(lo[0], lo[1], lo[2], lo[3]);
    }
    unsigned short h8[8], l8[8];
#pragma unroll
    for (int j = 0; j < 8; ++j) split2(wreg[j], h8[j], l8[j]);
    const int boff = ge * 64 + (gk ^ ((ge & 7) * 8));
    *(uint4*)&Bh[boff] = *(const uint4*)h8;
    *(uint4*)&Bl[boff] = *(const uint4*)l8;
  };

  issue(0);
  for (int k0 = 0; k0 < ND; k0 += 64) {
    commit();
    __syncthreads();
    if (k0 + 64 < ND) issue(k0 + 64);
#pragma unroll
    for (int ks = 0; ks < 2; ++ks) {
      const int koff = ks * 32 + (l >> 4) * 8;
      bf16x8 ah[2], alo[2], bh[2], blo[2];
#pragma unroll
      for (int mf = 0; mf < 2; ++mf) {
        const int r   = w * 32 + mf * 16 + (l & 15);
        const int off = r * 64 + (koff ^ ((r & 7) * 8));
        ah[mf]  = *(const bf16x8*)&Ah[off];
        alo[mf] = *(const bf16x8*)&Al[off];
      }
#pragma unroll
      for (int nf = 0; nf < 2; ++nf) {
        const int n   = nf * 16 + (l & 15);
        const int off = n * 64 + (koff ^ ((n & 7) * 8));
        bh[nf]  = *(const bf16x8*)&Bh[off];
        blo[nf] = *(const bf16x8*)&Bl[off];
      }
#pragma unroll
      for (int mf = 0; mf < 2; ++mf)
#pragma unroll
        for (int nf = 0; nf < 2; ++nf) {
          acc[mf][nf] = __builtin_amdgcn_mfma_f32_16x16x32_bf16(ah[mf],  bh[nf],  acc[mf][nf], 0, 0, 0);
          acc[mf][nf] = __builtin_amdgcn_mfma_f32_16x16x32_bf16(alo[mf], bh[nf],  acc[mf][nf], 0, 0, 0);
          acc[mf][nf] = __builtin_amdgcn_mfma_f32_16x16x32_bf16(ah[mf],  blo[nf], acc[mf][nf], 0, 0, 0);
        }
    }
    __syncthreads();
  }
  // transpose epilogue through LDS for coalesced [e][s] stores
#pragma unroll
  for (int mf = 0; mf < 2; ++mf)
#pragma unroll
    for (int nf = 0; nf < 2; ++nf)
#pragma unroll
      for (int j = 0; j < 4; ++j) {
        const int sl = w * 32 + mf * 16 + (l >> 4) * 4 + j;
        const int ec = nf * 16 + (l & 15);
        trans[sl * 33 + ec] = acc[mf][nf][j];
      }
  __syncthreads();
  const int eo = t >> 3, sc = (t & 7) * 16;
#pragma unroll
  for (int j4 = 0; j4 < 4; ++j4) {
    float4 v;
    v.x = trans[(sc + j4 * 4 + 0) * 33 + eo];
    v.y = trans[(sc + j4 * 4 + 1) * 33 + eo];
    v.z = trans[(sc + j4 * 4 + 2) * 33 + eo];
    v.w = trans[(sc + j4 * 4 + 3) * 33 + eo];
    *(float4*)&logitsT[((size_t)b * NE + eo) * NS + s0 + sc + j4 * 4] = v;
  }
}

// ---------------------------------------------------------------------------
// Kernel 2: 4 waves/block, single pass; per-wave top-16 via sorted registers,
// wave-0 merge, local-max-rescaled denom, fp64 recheck -> exact top-8.
// ---------------------------------------------------------------------------
__global__ __launch_bounds__(256) void k_topk(const float* __restrict__ logitsT,
                                              const float* __restrict__ x,
                                              const float* __restrict__ gw,
                                              float* __restrict__ tval,
                                              int* __restrict__ tidx) {
  const int be = blockIdx.x, b = be >> 5, e = be & 31;
  const float* row = logitsT + (size_t)be * NS;
  const int t = threadIdx.x, w = t >> 6, lane = t & 63;

  __shared__ float  cv[64];
  __shared__ int    cix[64];
  __shared__ double wsum[4];
  __shared__ float  smax;
  __shared__ int    gci[16];
  __shared__ float  glc[16];
  __shared__ double ginv;

  float v[8]; int si[8];
#pragma unroll
  for (int j = 0; j < 8; ++j) {
    const int s = w * 512 + lane + j * 64;
    v[j] = row[s]; si[j] = s;
  }
#pragma unroll
  for (int i = 0; i < 7; ++i)
#pragma unroll
    for (int j = 0; j < 7 - i; ++j) {
      const bool sw = (v[j + 1] > v[j]) || (v[j + 1] == v[j] && si[j + 1] < si[j]);
      const float tv = sw ? v[j + 1] : v[j];
      const int   ti = sw ? si[j + 1] : si[j];
      v[j + 1] = sw ? v[j] : v[j + 1];  si[j + 1] = sw ? si[j] : si[j + 1];
      v[j] = tv;  si[j] = ti;
    }
  const float mxl = v[0];
  double s8 = 1.0;
#pragma unroll
  for (int j = 1; j < 8; ++j) s8 += (double)expf(v[j] - mxl);

  for (int r = 0; r < 16; ++r) {
    float bp = v[0]; int bi = si[0]; int bl = lane;
#pragma unroll
    for (int off = 1; off < 64; off <<= 1) {
      const float op = __shfl_xor(bp, off);
      const int   oi = __shfl_xor(bi, off);
      const int   ol = __shfl_xor(bl, off);
      if (op > bp || (op == bp && oi < bi)) { bp = op; bi = oi; bl = ol; }
    }
    if (lane == 0) { cv[w * 16 + r] = bp; cix[w * 16 + r] = bi; }
    if (lane == bl) {
      v[0]=v[1]; v[1]=v[2]; v[2]=v[3]; v[3]=v[4]; v[4]=v[5]; v[5]=v[6]; v[6]=v[7]; v[7]=-INFINITY;
      si[0]=si[1]; si[1]=si[2]; si[2]=si[3]; si[3]=si[4]; si[4]=si[5]; si[5]=si[6]; si[6]=si[7]; si[7]=0x7fffffff;
    }
  }
  __syncthreads();
  if (w == 0) {
    float mv = cv[lane]; int mi = cix[lane];
    for (int r = 0; r < 16; ++r) {
      float bp = mv; int bi = mi; int bl = lane;
#pragma unroll
      for (int off = 1; off < 64; off <<= 1) {
        const float op = __shfl_xor(bp, off);
        const int   oi = __shfl_xor(bi, off);
        const int   ol = __shfl_xor(bl, off);
        if (op > bp || (op == bp && oi < bi)) { bp = op; bi = oi; bl = ol; }
      }
      if (lane == 0) { gci[r] = bi; if (r == 0) smax = bp; }
      if (lane == bl) { mv = -INFINITY; mi = 0x7fffffff; }
    }
  }
  __syncthreads();
  const float mx = smax;
  double lsum = s8 * (double)expf(mxl - mx);
#pragma unroll
  for (int off = 32; off; off >>= 1) lsum += __shfl_xor(lsum, off);
  if (lane == 0) wsum[w] = lsum;
  __syncthreads();
  if (t == 0) ginv = 1.0 / (wsum[0] + wsum[1] + wsum[2] + wsum[3]);

  const int kb = lane * 16;
  float gwl[16];
  *(float4*)&gwl[0]  = *(const float4*)&gw[(size_t)e * ND + kb];
  *(float4*)&gwl[4]  = *(const float4*)&gw[(size_t)e * ND + kb + 4];
  *(float4*)&gwl[8]  = *(const float4*)&gw[(size_t)e * ND + kb + 8];
  *(float4*)&gwl[12] = *(const float4*)&gw[(size_t)e * ND + kb + 12];
#pragma unroll
  for (int q = 0; q < 4; ++q) {
    const int c = w * 4 + q;
    const int ciq = gci[c];
    const float* xr = x + ((size_t)b * NS + ciq) * ND + kb;
    float xv[16];
    *(float4*)&xv[0]  = *(const float4*)&xr[0];
    *(float4*)&xv[4]  = *(const float4*)&xr[4];
    *(float4*)&xv[8]  = *(const float4*)&xr[8];
    *(float4*)&xv[12] = *(const float4*)&xr[12];
    double d = 0.0;
#pragma unroll
    for (int j2 = 0; j2 < 16; ++j2) d += (double)xv[j2] * (double)gwl[j2];
#pragma unroll
    for (int off = 32; off; off >>= 1) d += __shfl_xor(d, off);
    if (lane == 0) glc[c] = (float)d;
  }
  __syncthreads();
  if (t < 16) {
    const float mylc = glc[t]; const int myci = gci[t];
    int rank = 0;
#pragma unroll
    for (int c2 = 0; c2 < 16; ++c2) {
      if (c2 == t) continue;
      rank += (glc[c2] > mylc) || (glc[c2] == mylc && gci[c2] < myci);
    }
    if (rank < 8) {
      tval[be * 8 + rank] = (float)((double)expf(mylc - mx) * ginv);
      tidx[be * 8 + rank] = myci;
    }
  }
}

// ---------------------------------------------------------------------------
// Kernel 3: mux/merge -> single bf16 A as pre-swizzled 64x64 tiles
// [e][kt][ m*64 + ((g ^ (m&7))<<3) + (k&7) ],  g = (k&63)>>3, m = b.
// ---------------------------------------------------------------------------
__global__ __launch_bounds__(256) void k_merge(const float* __restrict__ x,
                                               const float* __restrict__ tval,
                                               const int* __restrict__ tidx,
                                               unsigned short* __restrict__ A1) {
  const int be = blockIdx.x;
  const int b  = be >> 5;
  const int e  = be & 31;
  const int t  = threadIdx.x;
  float4 acc = {0.f, 0.f, 0.f, 0.f};
#pragma unroll
  for (int k = 0; k < 8; ++k) {
    float v = tval[be * 8 + k];
    int   s = tidx[be * 8 + k];
    float4 xv = *(const float4*)&x[((size_t)b * NS + s) * ND + t * 4];
    acc.x += v * xv.x; acc.y += v * xv.y; acc.z += v * xv.z; acc.w += v * xv.w;
  }
  const int kt = t >> 4;
  const int g  = (t & 15) >> 1;
  const size_t off = ((size_t)(e * 16 + kt)) * 4096 + b * 64 + ((g ^ (b & 7)) << 3) + (t & 1) * 4;
  unsigned short h4[4] = {f2bf_rne(acc.x), f2bf_rne(acc.y), f2bf_rne(acc.z), f2bf_rne(acc.w)};
  *(ushort4*)&A1[off] = *(const ushort4*)h4;
}

// ---------------------------------------------------------------------------
// Kernels 4/5: per-expert FFN GEMM, single-bf16 MFMA (1 term), BN=64,
// LDS 32KB -> 4 blocks/CU. T3 2-phase pipeline, one barrier per K-tile:
//   A: global_load_lds DMA from pre-swizzled bf16 tiles, double-buffered.
//   W: column-run register prefetch issued one tile ahead (coalesced 256B
//      per wave-run), converted+ds_write_b128 after the MFMA phase.
// Waves 2x2: per-wave 32m x 32n.
// ---------------------------------------------------------------------------
template <int K, int N, bool GELU>
__global__ __launch_bounds__(256, 4) void k_ffn(const unsigned short* __restrict__ AT,
                                                const float* __restrict__ W,
                                                unsigned short* __restrict__ OT,
                                                float* __restrict__ Of) {
  constexpr int KT = K / 64;
  const int e  = blockIdx.y;
  const int n0 = blockIdx.x * 64;
  const int t  = threadIdx.x, l = t & 63, w = t >> 6;
  const int wr = w >> 1, wc = w & 1;

  __shared__ char smem[32768];
  // A buf d: smem + d*8192 ; B buf d: smem + 16384 + d*8192

  const float* Wbase = W + (size_t)e * (K + 1) * N;
  f32x4 acc[2][2] = {};

  const int wn  = l;              // W staging: column n0+wn
  const int wk0 = w * 8;          // k-run base per wave
  float wreg[2][8];

  auto issueW = [&](int kt) {
    const float* Wg = Wbase + (size_t)(kt * 64) * N + n0 + wn;
#pragma unroll
    for (int rn = 0; rn < 2; ++rn)
#pragma unroll
      for (int j = 0; j < 8; ++j)
        wreg[rn][j] = Wg[(size_t)(wk0 + rn * 32 + j) * N];
  };
  auto issueA = [&](int kt, int dst) {
    const unsigned short* at = AT + ((size_t)(e * KT + kt)) * 4096;
    char* Ab = smem + dst * 8192;
#pragma unroll
    for (int p = 0; p < 2; ++p)
      gload_lds16(at + p * 2048 + t * 8, Ab + p * 4096 + w * 1024);
  };
  auto commitW = [&](int dst) {
    short* Bb = (short*)(smem + 16384 + dst * 8192);
#pragma unroll
    for (int rn = 0; rn < 2; ++rn) {
      const int kr = (wk0 + rn * 32) >> 3;
      unsigned short s8[8];
#pragma unroll
      for (int j = 0; j < 8; ++j) s8[j] = f2bf_rne(wreg[rn][j]);
      *(uint4*)&Bb[wn * 64 + ((kr ^ (wn & 7)) << 3)] = *(const uint4*)s8;
    }
  };
  auto mfma_phase = [&](int cur) {
    const short* Ab = (const short*)(smem + cur * 8192);
    const short* Bb = (const short*)(smem + 16384 + cur * 8192);
#pragma unroll
    for (int ks = 0; ks < 2; ++ks) {
      const int g8 = ks * 4 + (l >> 4);
      bf16x8 a[2], bb[2];
#pragma unroll
      for (int mf = 0; mf < 2; ++mf) {
        const int m = wr * 32 + mf * 16 + (l & 15);
        a[mf] = *(const bf16x8*)&Ab[m * 64 + ((g8 ^ (m & 7)) << 3)];
      }
#pragma unroll
      for (int nf = 0; nf < 2; ++nf) {
        const int n = wc * 32 + nf * 16 + (l & 15);
        bb[nf] = *(const bf16x8*)&Bb[n * 64 + ((g8 ^ (n & 7)) << 3)];
      }
#pragma unroll
      for (int mf = 0; mf < 2; ++mf)
#pragma unroll
        for (int nf = 0; nf < 2; ++nf)
          acc[mf][nf] = __builtin_amdgcn_mfma_f32_16x16x32_bf16(a[mf], bb[nf], acc[mf][nf], 0, 0, 0);
    }
  };

  issueW(0); issueA(0, 0);
  commitW(0);
  __syncthreads();
  if (KT > 1) { issueW(1); issueA(1, 1); }
  int cur = 0;
  for (int kt = 0; kt < KT; ++kt) {
    mfma_phase(cur);
    if (kt + 1 < KT) {
      commitW(cur ^ 1);
      __syncthreads();
      if (kt + 2 < KT) { issueW(kt + 2); issueA(kt + 2, cur); }
      cur ^= 1;
    }
  }
  __syncthreads();

  // ---------------- epilogue ----------------
  if (GELU) {
    unsigned short* transU = (unsigned short*)smem;  // [64][72]
#pragma unroll
    for (int nf = 0; nf < 2; ++nf) {
      const int c = wc * 32 + nf * 16 + (l & 15);
      const float bias = Wbase[(size_t)K * N + n0 + c];
#pragma unroll
      for (int mf = 0; mf < 2; ++mf)
#pragma unroll
        for (int j = 0; j < 4; ++j) {
          const int m = wr * 32 + mf * 16 + (l >> 4) * 4 + j;
          float vv = acc[mf][nf][j] + bias;
          vv = 0.5f * vv * (1.0f + erff(vv * 0.70710678118654752440f));
          transU[m * 72 + c] = f2bf_rne(vv);
        }
    }
    __syncthreads();
    const int m  = t >> 2;
    const int c0 = (t & 3) * 16;
    const size_t tb = ((size_t)(e * (N / 64) + blockIdx.x)) * 4096;
    uint4 v0 = *(const uint4*)&transU[m * 72 + c0];
    uint4 v1 = *(const uint4*)&transU[m * 72 + c0 + 8];
    const int g0 = c0 >> 3;
    *(uint4*)&OT[tb + m * 64 + ((g0 ^ (m & 7)) << 3)]       = v0;
    *(uint4*)&OT[tb + m * 64 + (((g0 + 1) ^ (m & 7)) << 3)] = v1;
  } else {
    float* transF = (float*)smem;  // [64][68]
#pragma unroll
    for (int nf = 0; nf < 2; ++nf) {
      const int c = wc * 32 + nf * 16 + (l & 15);
      const float bias = Wbase[(size_t)K * N + n0 + c];
#pragma unroll
      for (int mf = 0; mf < 2; ++mf)
#pragma unroll
        for (int j = 0; j < 4; ++j) {
          const int m = wr * 32 + mf * 16 + (l >> 4) * 4 + j;
          transF[m * 68 + c] = acc[mf][nf][j] + bias;
        }
    }
    __syncthreads();
    const int m  = t >> 2;
    const int c0 = (t & 3) * 16;
    float* og = Of + ((size_t)m * NE + e) * ND + n0 + c0;
    *(float4*)&og[0]  = *(const float4*)&transF[m * 68 + c0];
    *(float4*)&og[4]  = *(const float4*)&transF[m * 68 + c0 + 4];
    *(float4*)&og[8]  = *(const float4*)&transF[m * 68 + c0 + 8];
    *(float4*)&og[12] = *(const float4*)&transF[m * 68 + c0 + 12];
  }
}

// ---------------------------------------------------------------------------
// Kernel 6: demux/scatter (deterministic, atomic-free, zero-fills).
// ---------------------------------------------------------------------------
__global__ __launch_bounds__(256) void k_scatter(const float* __restrict__ Obuf,
                                                 const float* __restrict__ tval,
                                                 const int* __restrict__ tidx,
                                                 float* __restrict__ out) {
  const int s = blockIdx.x;
  const int b = blockIdx.y;
  const int t = threadIdx.x;
  __shared__ unsigned long long masks[4];

  const int myIdx = tidx[b * 256 + t];
  unsigned long long m = __ballot(myIdx == s);
  if ((t & 63) == 0) masks[t >> 6] = m;
  __syncthreads();

  float4 acc = {0.f, 0.f, 0.f, 0.f};
#pragma unroll
  for (int w = 0; w < 4; ++w) {
    unsigned long long mm = masks[w];
    while (mm) {
      int bit = __ffsll(mm) - 1;
      mm &= mm - 1;
      int r = w * 64 + bit;
      float v = tval[b * 256 + r];
      const float4 ov = *(const float4*)&Obuf[((size_t)b * NE + (r >> 3)) * ND + t * 4];
      acc.x += v * ov.x; acc.y += v * ov.y; acc.z += v * ov.z; acc.w += v * ov.w;
    }
  }
  *(float4*)&out[((size_t)b * NS + s) * ND + t * 4] = acc;
}

// ---------------------------------------------------------------------------
extern "C" void kernel_launch(void* const* d_in, const int* in_sizes, int n_in,
                              void* d_out, int out_size, void* d_ws, size_t ws_size,
                              hipStream_t stream) {
  const float* x  = (const float*)d_in[0];
  const float* gw = (const float*)d_in[1];
  const float* w1 = (const float*)d_in[3];
  const float* w2 = (const float*)d_in[4];
  float* out = (float*)d_out;

  char* ws = (char*)d_ws;
  float* logitsT     = (float*)ws;                         // 16,777,216 B
  float* tval        = (float*)(ws + 16777216);            //     65,536 B
  int*   tidx        = (int*)  (ws + 16842752);            //     65,536 B
  unsigned short* A1 = (unsigned short*)(ws + 16908288);   //  4,194,304 B (bf16 tiles)
  unsigned short* Hb = (unsigned short*)(ws + 21102592);   // 16,777,216 B (bf16 tiles)
  float* Obuf        = (float*)(ws + 37879808);            //  8,388,608 B

  k_gate_mfma<<<dim3(NS / 128, NB), 256, 0, stream>>>(x, gw, logitsT);
  k_topk<<<NB * NE, 256, 0, stream>>>(logitsT, x, gw, tval, tidx);
  k_merge<<<NB * NE, 256, 0, stream>>>(x, tval, tidx, A1);
  k_ffn<ND, NH, true ><<<dim3(NH / 64, NE), 256, 0, stream>>>(A1, w1, Hb, nullptr);
  k_ffn<NH, ND, false><<<dim3(ND / 64, NE), 256, 0, stream>>>(Hb, w2, nullptr, Obuf);
  k_scatter<<<dim3(NS, NB), 256, 0, stream>>>(Obuf, tval, tidx, out);
}

// Round 7
// 570.856 us; speedup vs baseline: 1.3749x; 1.0298x over previous
//
#include <hip/hip_runtime.h>
#include <hip/hip_bf16.h>
#include <math.h>

constexpr int NB = 64;     // batch
constexpr int NS = 2048;   // tokens
constexpr int ND = 1024;   // model dim
constexpr int NE = 32;     // experts
constexpr int NH = 4096;   // hidden
constexpr int NK = 8;      // top-k tokens per expert

typedef short bf16x8 __attribute__((ext_vector_type(8)));
typedef float f32x4  __attribute__((ext_vector_type(4)));

__device__ __forceinline__ unsigned short f2bf_rne(float v) {
  unsigned u = __builtin_bit_cast(unsigned, v);
  u += 0x7fffu + ((u >> 16) & 1u);
  return (unsigned short)(u >> 16);
}

__device__ __forceinline__ void gload_lds16(const void* g, void* l) {
  __builtin_amdgcn_global_load_lds(
      (const __attribute__((address_space(1))) unsigned*)g,
      (__attribute__((address_space(3))) unsigned*)l, 16, 0, 0);
}

// ---------------------------------------------------------------------------
// Kernel 1: gating GEMM, single-term bf16 MFMA (logit err ~2e-3 — top-16
// superset + denominator stay safe; exact ordering restored by fp64 recheck
// in k_topk). Double-buffered LDS, issue->mfma->commit, 1 barrier/K-tile.
// ---------------------------------------------------------------------------
__global__ __launch_bounds__(256) void k_gate_mfma(const float* __restrict__ x,
                                                   const float* __restrict__ gw,
                                                   float* __restrict__ logitsT) {
  const int b  = blockIdx.y;
  const int s0 = blockIdx.x * 128;
  const int t  = threadIdx.x;
  const int l  = t & 63;
  const int w  = t >> 6;

  __shared__ char smem[40960];
  // Ab[d] @ d*16384 : [128][64] swz bf16 ; Bb[d] @ 32768 + d*4096 : [32][64]
  float* trans = (float*)smem;  // epilogue reuse

  f32x4 acc[2][2] = {};

  const int xr_ = t >> 4, xc = (t & 15) * 4;   // x staging: 16 thr/row
  const int ge = t >> 3,  gk = (t & 7) * 8;    // gw staging: 8 thr/row

  float xreg[8][4];
  float wreg[8];

  auto issue = [&](int kt) {
    const int k0 = kt * 64;
#pragma unroll
    for (int p = 0; p < 8; ++p) {
      const int r = p * 16 + xr_;
      *(float4*)xreg[p] = *(const float4*)&x[((size_t)b * NS + s0 + r) * ND + k0 + xc];
    }
    *(float4*)&wreg[0] = *(const float4*)&gw[(size_t)ge * ND + k0 + gk];
    *(float4*)&wreg[4] = *(const float4*)&gw[(size_t)ge * ND + k0 + gk + 4];
  };
  auto commit = [&](int dst) {
    short* Ah = (short*)(smem + dst * 16384);
    short* Bh = (short*)(smem + 32768 + dst * 4096);
#pragma unroll
    for (int p = 0; p < 8; ++p) {
      const int r = p * 16 + xr_;
      unsigned short h[4];
#pragma unroll
      for (int j = 0; j < 4; ++j) h[j] = f2bf_rne(xreg[p][j]);
      const int off = r * 64 + (xc ^ ((r & 7) * 8));
      *(ushort4*)&Ah[off] = *(const ushort4*)h;
    }
    unsigned short h8[8];
#pragma unroll
    for (int j = 0; j < 8; ++j) h8[j] = f2bf_rne(wreg[j]);
    const int boff = ge * 64 + (gk ^ ((ge & 7) * 8));
    *(uint4*)&Bh[boff] = *(const uint4*)h8;
  };
  auto mfma_phase = [&](int cur) {
    const short* Ah = (const short*)(smem + cur * 16384);
    const short* Bh = (const short*)(smem + 32768 + cur * 4096);
#pragma unroll
    for (int ks = 0; ks < 2; ++ks) {
      const int koff = ks * 32 + (l >> 4) * 8;
      bf16x8 a[2], bb[2];
#pragma unroll
      for (int mf = 0; mf < 2; ++mf) {
        const int r = w * 32 + mf * 16 + (l & 15);
        a[mf] = *(const bf16x8*)&Ah[r * 64 + (koff ^ ((r & 7) * 8))];
      }
#pragma unroll
      for (int nf = 0; nf < 2; ++nf) {
        const int n = nf * 16 + (l & 15);
        bb[nf] = *(const bf16x8*)&Bh[n * 64 + (koff ^ ((n & 7) * 8))];
      }
#pragma unroll
      for (int mf = 0; mf < 2; ++mf)
#pragma unroll
        for (int nf = 0; nf < 2; ++nf)
          acc[mf][nf] = __builtin_amdgcn_mfma_f32_16x16x32_bf16(a[mf], bb[nf], acc[mf][nf], 0, 0, 0);
    }
  };

  issue(0);
  commit(0);
  __syncthreads();
  int cur = 0;
  for (int kt = 0; kt < ND / 64; ++kt) {
    const bool more = (kt + 1 < ND / 64);
    if (more) issue(kt + 1);
    mfma_phase(cur);
    if (more) commit(cur ^ 1);
    __syncthreads();
    cur ^= 1;
  }

  // transpose epilogue through LDS for coalesced [e][s] stores
#pragma unroll
  for (int mf = 0; mf < 2; ++mf)
#pragma unroll
    for (int nf = 0; nf < 2; ++nf)
#pragma unroll
      for (int j = 0; j < 4; ++j) {
        const int sl = w * 32 + mf * 16 + (l >> 4) * 4 + j;
        const int ec = nf * 16 + (l & 15);
        trans[sl * 33 + ec] = acc[mf][nf][j];
      }
  __syncthreads();
  const int eo = t >> 3, sc = (t & 7) * 16;
#pragma unroll
  for (int j4 = 0; j4 < 4; ++j4) {
    float4 v;
    v.x = trans[(sc + j4 * 4 + 0) * 33 + eo];
    v.y = trans[(sc + j4 * 4 + 1) * 33 + eo];
    v.z = trans[(sc + j4 * 4 + 2) * 33 + eo];
    v.w = trans[(sc + j4 * 4 + 3) * 33 + eo];
    *(float4*)&logitsT[((size_t)b * NE + eo) * NS + s0 + sc + j4 * 4] = v;
  }
}

// ---------------------------------------------------------------------------
// Kernel 2: 4 waves/block, single pass; per-wave top-16 via sorted registers,
// wave-0 merge, local-max-rescaled denom, fp64 recheck -> exact top-8.
// ---------------------------------------------------------------------------
__global__ __launch_bounds__(256) void k_topk(const float* __restrict__ logitsT,
                                              const float* __restrict__ x,
                                              const float* __restrict__ gw,
                                              float* __restrict__ tval,
                                              int* __restrict__ tidx) {
  const int be = blockIdx.x, b = be >> 5, e = be & 31;
  const float* row = logitsT + (size_t)be * NS;
  const int t = threadIdx.x, w = t >> 6, lane = t & 63;

  __shared__ float  cv[64];
  __shared__ int    cix[64];
  __shared__ double wsum[4];
  __shared__ float  smax;
  __shared__ int    gci[16];
  __shared__ float  glc[16];
  __shared__ double ginv;

  float v[8]; int si[8];
#pragma unroll
  for (int j = 0; j < 8; ++j) {
    const int s = w * 512 + lane + j * 64;
    v[j] = row[s]; si[j] = s;
  }
#pragma unroll
  for (int i = 0; i < 7; ++i)
#pragma unroll
    for (int j = 0; j < 7 - i; ++j) {
      const bool sw = (v[j + 1] > v[j]) || (v[j + 1] == v[j] && si[j + 1] < si[j]);
      const float tv = sw ? v[j + 1] : v[j];
      const int   ti = sw ? si[j + 1] : si[j];
      v[j + 1] = sw ? v[j] : v[j + 1];  si[j + 1] = sw ? si[j] : si[j + 1];
      v[j] = tv;  si[j] = ti;
    }
  const float mxl = v[0];
  double s8 = 1.0;
#pragma unroll
  for (int j = 1; j < 8; ++j) s8 += (double)expf(v[j] - mxl);

  for (int r = 0; r < 16; ++r) {
    float bp = v[0]; int bi = si[0]; int bl = lane;
#pragma unroll
    for (int off = 1; off < 64; off <<= 1) {
      const float op = __shfl_xor(bp, off);
      const int   oi = __shfl_xor(bi, off);
      const int   ol = __shfl_xor(bl, off);
      if (op > bp || (op == bp && oi < bi)) { bp = op; bi = oi; bl = ol; }
    }
    if (lane == 0) { cv[w * 16 + r] = bp; cix[w * 16 + r] = bi; }
    if (lane == bl) {
      v[0]=v[1]; v[1]=v[2]; v[2]=v[3]; v[3]=v[4]; v[4]=v[5]; v[5]=v[6]; v[6]=v[7]; v[7]=-INFINITY;
      si[0]=si[1]; si[1]=si[2]; si[2]=si[3]; si[3]=si[4]; si[4]=si[5]; si[5]=si[6]; si[6]=si[7]; si[7]=0x7fffffff;
    }
  }
  __syncthreads();
  if (w == 0) {
    float mv = cv[lane]; int mi = cix[lane];
    for (int r = 0; r < 16; ++r) {
      float bp = mv; int bi = mi; int bl = lane;
#pragma unroll
      for (int off = 1; off < 64; off <<= 1) {
        const float op = __shfl_xor(bp, off);
        const int   oi = __shfl_xor(bi, off);
        const int   ol = __shfl_xor(bl, off);
        if (op > bp || (op == bp && oi < bi)) { bp = op; bi = oi; bl = ol; }
      }
      if (lane == 0) { gci[r] = bi; if (r == 0) smax = bp; }
      if (lane == bl) { mv = -INFINITY; mi = 0x7fffffff; }
    }
  }
  __syncthreads();
  const float mx = smax;
  double lsum = s8 * (double)expf(mxl - mx);
#pragma unroll
  for (int off = 32; off; off >>= 1) lsum += __shfl_xor(lsum, off);
  if (lane == 0) wsum[w] = lsum;
  __syncthreads();
  if (t == 0) ginv = 1.0 / (wsum[0] + wsum[1] + wsum[2] + wsum[3]);

  const int kb = lane * 16;
  float gwl[16];
  *(float4*)&gwl[0]  = *(const float4*)&gw[(size_t)e * ND + kb];
  *(float4*)&gwl[4]  = *(const float4*)&gw[(size_t)e * ND + kb + 4];
  *(float4*)&gwl[8]  = *(const float4*)&gw[(size_t)e * ND + kb + 8];
  *(float4*)&gwl[12] = *(const float4*)&gw[(size_t)e * ND + kb + 12];
#pragma unroll
  for (int q = 0; q < 4; ++q) {
    const int c = w * 4 + q;
    const int ciq = gci[c];
    const float* xr = x + ((size_t)b * NS + ciq) * ND + kb;
    float xv[16];
    *(float4*)&xv[0]  = *(const float4*)&xr[0];
    *(float4*)&xv[4]  = *(const float4*)&xr[4];
    *(float4*)&xv[8]  = *(const float4*)&xr[8];
    *(float4*)&xv[12] = *(const float4*)&xr[12];
    double d = 0.0;
#pragma unroll
    for (int j2 = 0; j2 < 16; ++j2) d += (double)xv[j2] * (double)gwl[j2];
#pragma unroll
    for (int off = 32; off; off >>= 1) d += __shfl_xor(d, off);
    if (lane == 0) glc[c] = (float)d;
  }
  __syncthreads();
  if (t < 16) {
    const float mylc = glc[t]; const int myci = gci[t];
    int rank = 0;
#pragma unroll
    for (int c2 = 0; c2 < 16; ++c2) {
      if (c2 == t) continue;
      rank += (glc[c2] > mylc) || (glc[c2] == mylc && gci[c2] < myci);
    }
    if (rank < 8) {
      tval[be * 8 + rank] = (float)((double)expf(mylc - mx) * ginv);
      tidx[be * 8 + rank] = myci;
    }
  }
}

// ---------------------------------------------------------------------------
// Kernel 3: mux/merge -> single bf16 A as pre-swizzled 64x64 tiles.
// ---------------------------------------------------------------------------
__global__ __launch_bounds__(256) void k_merge(const float* __restrict__ x,
                                               const float* __restrict__ tval,
                                               const int* __restrict__ tidx,
                                               unsigned short* __restrict__ A1) {
  const int be = blockIdx.x;
  const int b  = be >> 5;
  const int e  = be & 31;
  const int t  = threadIdx.x;
  float4 acc = {0.f, 0.f, 0.f, 0.f};
#pragma unroll
  for (int k = 0; k < 8; ++k) {
    float v = tval[be * 8 + k];
    int   s = tidx[be * 8 + k];
    float4 xv = *(const float4*)&x[((size_t)b * NS + s) * ND + t * 4];
    acc.x += v * xv.x; acc.y += v * xv.y; acc.z += v * xv.z; acc.w += v * xv.w;
  }
  const int kt = t >> 4;
  const int g  = (t & 15) >> 1;
  const size_t off = ((size_t)(e * 16 + kt)) * 4096 + b * 64 + ((g ^ (b & 7)) << 3) + (t & 1) * 4;
  unsigned short h4[4] = {f2bf_rne(acc.x), f2bf_rne(acc.y), f2bf_rne(acc.z), f2bf_rne(acc.w)};
  *(ushort4*)&A1[off] = *(const ushort4*)h4;
}

// ---------------------------------------------------------------------------
// Kernels 4/5: per-expert FFN GEMM, single-bf16 MFMA, BN=64, 32KB LDS.
// Pipeline per K-tile: {issueW(kt+1); issueA(kt+1)} -> mfma(kt) ->
// commitW(kt+1) -> barrier. W-load latency hides under the MFMA phase.
// ---------------------------------------------------------------------------
template <int K, int N, bool GELU>
__global__ __launch_bounds__(256, 4) void k_ffn(const unsigned short* __restrict__ AT,
                                                const float* __restrict__ W,
                                                unsigned short* __restrict__ OT,
                                                float* __restrict__ Of) {
  constexpr int KT = K / 64;
  const int e  = blockIdx.y;
  const int n0 = blockIdx.x * 64;
  const int t  = threadIdx.x, l = t & 63, w = t >> 6;
  const int wr = w >> 1, wc = w & 1;

  __shared__ char smem[32768];
  // A buf d: smem + d*8192 ; B buf d: smem + 16384 + d*8192

  const float* Wbase = W + (size_t)e * (K + 1) * N;
  f32x4 acc[2][2] = {};

  const int wn  = l;              // W staging: column n0+wn
  const int wk0 = w * 8;          // k-run base per wave
  float wreg[2][8];

  auto issueW = [&](int kt) {
    const float* Wg = Wbase + (size_t)(kt * 64) * N + n0 + wn;
#pragma unroll
    for (int rn = 0; rn < 2; ++rn)
#pragma unroll
      for (int j = 0; j < 8; ++j)
        wreg[rn][j] = Wg[(size_t)(wk0 + rn * 32 + j) * N];
  };
  auto issueA = [&](int kt, int dst) {
    const unsigned short* at = AT + ((size_t)(e * KT + kt)) * 4096;
    char* Ab = smem + dst * 8192;
#pragma unroll
    for (int p = 0; p < 2; ++p)
      gload_lds16(at + p * 2048 + t * 8, Ab + p * 4096 + w * 1024);
  };
  auto commitW = [&](int dst) {
    short* Bb = (short*)(smem + 16384 + dst * 8192);
#pragma unroll
    for (int rn = 0; rn < 2; ++rn) {
      const int kr = (wk0 + rn * 32) >> 3;
      unsigned short s8[8];
#pragma unroll
      for (int j = 0; j < 8; ++j) s8[j] = f2bf_rne(wreg[rn][j]);
      *(uint4*)&Bb[wn * 64 + ((kr ^ (wn & 7)) << 3)] = *(const uint4*)s8;
    }
  };
  auto mfma_phase = [&](int cur) {
    const short* Ab = (const short*)(smem + cur * 8192);
    const short* Bb = (const short*)(smem + 16384 + cur * 8192);
#pragma unroll
    for (int ks = 0; ks < 2; ++ks) {
      const int g8 = ks * 4 + (l >> 4);
      bf16x8 a[2], bb[2];
#pragma unroll
      for (int mf = 0; mf < 2; ++mf) {
        const int m = wr * 32 + mf * 16 + (l & 15);
        a[mf] = *(const bf16x8*)&Ab[m * 64 + ((g8 ^ (m & 7)) << 3)];
      }
#pragma unroll
      for (int nf = 0; nf < 2; ++nf) {
        const int n = wc * 32 + nf * 16 + (l & 15);
        bb[nf] = *(const bf16x8*)&Bb[n * 64 + ((g8 ^ (n & 7)) << 3)];
      }
#pragma unroll
      for (int mf = 0; mf < 2; ++mf)
#pragma unroll
        for (int nf = 0; nf < 2; ++nf)
          acc[mf][nf] = __builtin_amdgcn_mfma_f32_16x16x32_bf16(a[mf], bb[nf], acc[mf][nf], 0, 0, 0);
    }
  };

  issueW(0); issueA(0, 0);
  commitW(0);
  __syncthreads();
  int cur = 0;
  for (int kt = 0; kt < KT; ++kt) {
    const bool more = (kt + 1 < KT);
    if (more) { issueW(kt + 1); issueA(kt + 1, cur ^ 1); }
    mfma_phase(cur);
    if (more) commitW(cur ^ 1);
    __syncthreads();
    cur ^= 1;
  }

  // ---------------- epilogue ----------------
  if (GELU) {
    unsigned short* transU = (unsigned short*)smem;  // [64][72]
#pragma unroll
    for (int nf = 0; nf < 2; ++nf) {
      const int c = wc * 32 + nf * 16 + (l & 15);
      const float bias = Wbase[(size_t)K * N + n0 + c];
#pragma unroll
      for (int mf = 0; mf < 2; ++mf)
#pragma unroll
        for (int j = 0; j < 4; ++j) {
          const int m = wr * 32 + mf * 16 + (l >> 4) * 4 + j;
          float vv = acc[mf][nf][j] + bias;
          vv = 0.5f * vv * (1.0f + erff(vv * 0.70710678118654752440f));
          transU[m * 72 + c] = f2bf_rne(vv);
        }
    }
    __syncthreads();
    const int m  = t >> 2;
    const int c0 = (t & 3) * 16;
    const size_t tb = ((size_t)(e * (N / 64) + blockIdx.x)) * 4096;
    uint4 v0 = *(const uint4*)&transU[m * 72 + c0];
    uint4 v1 = *(const uint4*)&transU[m * 72 + c0 + 8];
    const int g0 = c0 >> 3;
    *(uint4*)&OT[tb + m * 64 + ((g0 ^ (m & 7)) << 3)]       = v0;
    *(uint4*)&OT[tb + m * 64 + (((g0 + 1) ^ (m & 7)) << 3)] = v1;
  } else {
    float* transF = (float*)smem;  // [64][68]
#pragma unroll
    for (int nf = 0; nf < 2; ++nf) {
      const int c = wc * 32 + nf * 16 + (l & 15);
      const float bias = Wbase[(size_t)K * N + n0 + c];
#pragma unroll
      for (int mf = 0; mf < 2; ++mf)
#pragma unroll
        for (int j = 0; j < 4; ++j) {
          const int m = wr * 32 + mf * 16 + (l >> 4) * 4 + j;
          transF[m * 68 + c] = acc[mf][nf][j] + bias;
        }
    }
    __syncthreads();
    const int m  = t >> 2;
    const int c0 = (t & 3) * 16;
    float* og = Of + ((size_t)m * NE + e) * ND + n0 + c0;
    *(float4*)&og[0]  = *(const float4*)&transF[m * 68 + c0];
    *(float4*)&og[4]  = *(const float4*)&transF[m * 68 + c0 + 4];
    *(float4*)&og[8]  = *(const float4*)&transF[m * 68 + c0 + 8];
    *(float4*)&og[12] = *(const float4*)&transF[m * 68 + c0 + 12];
  }
}

// ---------------------------------------------------------------------------
// Kernel 6: demux/scatter, 8 tokens per block. One tidx load + 8 ballots,
// masks in LDS; deterministic fixed-order accumulation; zero-fills.
// ---------------------------------------------------------------------------
__global__ __launch_bounds__(256) void k_scatter(const float* __restrict__ Obuf,
                                                 const float* __restrict__ tval,
                                                 const int* __restrict__ tidx,
                                                 float* __restrict__ out) {
  const int s0 = blockIdx.x * 8;
  const int b  = blockIdx.y;
  const int t  = threadIdx.x;
  const int w  = t >> 6;
  __shared__ unsigned long long masks[8][4];

  const int myIdx = tidx[b * 256 + t];  // slot t = e*8 + k
#pragma unroll
  for (int j = 0; j < 8; ++j) {
    unsigned long long m = __ballot(myIdx == s0 + j);
    if ((t & 63) == 0) masks[j][w] = m;
  }
  __syncthreads();

#pragma unroll
  for (int j = 0; j < 8; ++j) {
    float4 acc = {0.f, 0.f, 0.f, 0.f};
#pragma unroll
    for (int q = 0; q < 4; ++q) {
      unsigned long long mm = masks[j][q];
      while (mm) {
        int bit = __ffsll(mm) - 1;
        mm &= mm - 1;
        int r = q * 64 + bit;
        float v = tval[b * 256 + r];
        const float4 ov = *(const float4*)&Obuf[((size_t)b * NE + (r >> 3)) * ND + t * 4];
        acc.x += v * ov.x; acc.y += v * ov.y; acc.z += v * ov.z; acc.w += v * ov.w;
      }
    }
    *(float4*)&out[((size_t)b * NS + s0 + j) * ND + t * 4] = acc;
  }
}

// ---------------------------------------------------------------------------
extern "C" void kernel_launch(void* const* d_in, const int* in_sizes, int n_in,
                              void* d_out, int out_size, void* d_ws, size_t ws_size,
                              hipStream_t stream) {
  const float* x  = (const float*)d_in[0];
  const float* gw = (const float*)d_in[1];
  const float* w1 = (const float*)d_in[3];
  const float* w2 = (const float*)d_in[4];
  float* out = (float*)d_out;

  char* ws = (char*)d_ws;
  float* logitsT     = (float*)ws;                         // 16,777,216 B
  float* tval        = (float*)(ws + 16777216);            //     65,536 B
  int*   tidx        = (int*)  (ws + 16842752);            //     65,536 B
  unsigned short* A1 = (unsigned short*)(ws + 16908288);   //  4,194,304 B (bf16 tiles)
  unsigned short* Hb = (unsigned short*)(ws + 21102592);   // 16,777,216 B (bf16 tiles)
  float* Obuf        = (float*)(ws + 37879808);            //  8,388,608 B

  k_gate_mfma<<<dim3(NS / 128, NB), 256, 0, stream>>>(x, gw, logitsT);
  k_topk<<<NB * NE, 256, 0, stream>>>(logitsT, x, gw, tval, tidx);
  k_merge<<<NB * NE, 256, 0, stream>>>(x, tval, tidx, A1);
  k_ffn<ND, NH, true ><<<dim3(NH / 64, NE), 256, 0, stream>>>(A1, w1, Hb, nullptr);
  k_ffn<NH, ND, false><<<dim3(ND / 64, NE), 256, 0, stream>>>(Hb, w2, nullptr, Obuf);
  k_scatter<<<dim3(NS / 8, NB), 256, 0, stream>>>(Obuf, tval, tidx, out);
}